// Round 15
// baseline (188.970 us; speedup 1.0000x reference)
//
#include <hip/hip_runtime.h>

// ---------------------------------------------------------------------------
// AttentionFuse: out[b,d] = mean_s( softmax((x Wq + bq)(x Wk + bk)^T / 32) @ (x Wv + bv) )
// Algebra:
//   mean_s(attn @ V) = sum_t a[t] V[t,:]  =>  out = (a^T x) Wv + bv   (V GEMM gone)
//   S = x (Wq Wk^T) x^T  =>  y = x Mt^T, Mt = Wk Wq^T (2.1 GF)  =>  S = y x^T
//   bias: P[s,t] = exp(scale*S + c[t]),  c[t] = scale * x[t].u,  u = Wk bq
// R15: R14's MX-scaled fp8 MFMA kept; __launch_bounds__(512,2) -> (512,1).
//   LDS=128KiB forces 1 block/CU anyway; the old bound capped VGPRs at 128
//   and spilled the v8i32 MFMA operands to scratch (+31MB FETCH/WRITE in R14).
//   (512,1) = 256 VGPRs at identical occupancy.
// ---------------------------------------------------------------------------

using bf16x8 = __attribute__((ext_vector_type(8))) __bf16;
using u16x8  = __attribute__((ext_vector_type(8))) unsigned short;
using f32x4  = __attribute__((ext_vector_type(4))) float;
using f32x2  = __attribute__((ext_vector_type(2))) float;
using i32x4  = __attribute__((ext_vector_type(4))) int;
using i32x8  = __attribute__((ext_vector_type(8))) int;

#define NB 8
#define SEQ 2048
#define DIM 1024
#define MTOT (NB * SEQ)          // 16384

__device__ __forceinline__ unsigned short f2bf(float f) {
    unsigned int u = __float_as_uint(f);
    u = u + 0x7FFFu + ((u >> 16) & 1u);   // RNE
    return (unsigned short)(u >> 16);
}
__device__ __forceinline__ float bf2f(unsigned short h) {
    return __uint_as_float(((unsigned int)h) << 16);
}
// byte position of element k within a permuted 128-elem fp8 K-block
__device__ __forceinline__ int perm128(int n) {
    return (n & ~127) + ((n >> 3) & 3) * 32 + ((n & 127) >> 5) * 8 + (n & 7);
}

__device__ __forceinline__ void async16(const unsigned short* g, unsigned short* l) {
    __builtin_amdgcn_global_load_lds(
        (const __attribute__((address_space(1))) void*)g,
        (__attribute__((address_space(3))) void*)l, 16, 0, 0);
}
__device__ __forceinline__ void async16b(const unsigned char* g, unsigned char* l) {
    __builtin_amdgcn_global_load_lds(
        (const __attribute__((address_space(1))) void*)g,
        (__attribute__((address_space(3))) void*)l, 16, 0, 0);
}
// MX-scaled fp8 MFMA, K=128, unit scales (E8M0 0x7F = 2^0); fmt 0 = e4m3
__device__ __forceinline__ f32x4 mfma128(i32x8 a, i32x8 b, f32x4 c) {
    return __builtin_amdgcn_mfma_scale_f32_16x16x128_f8f6f4(
        a, b, c, 0, 0, 0, 0x7f7f7f7f, 0, 0x7f7f7f7f);
}
// forced 16B LDS read (one ds_read_b128)
__device__ __forceinline__ i32x4 ds_read128(const unsigned char* base, int off) {
    unsigned addr = (unsigned)(size_t)(
        (const __attribute__((address_space(3))) unsigned char*)base + off);
    i32x4 r;
    asm volatile("ds_read_b128 %0, %1" : "=v"(r) : "v"(addr));
    return r;
}

// ---------------- K0 (merged prep): cvt_w x2, u = Wk bq, out = bv ----------------
__global__ __launch_bounds__(256) void k_prep(const float* __restrict__ Wk,
                                              const float* __restrict__ Wq,
                                              const float* __restrict__ bq,
                                              const float* __restrict__ bv,
                                              unsigned short* __restrict__ wkb,
                                              unsigned short* __restrict__ wqb,
                                              float* __restrict__ u,
                                              float* __restrict__ out) {
    const int bid = blockIdx.x;
    if (bid < 2048) {                       // Wk,Wq fp32 -> bf16
        const float* src = (bid >= 1024) ? Wq : Wk;
        unsigned short* dst = (bid >= 1024) ? wqb : wkb;
        size_t i = ((size_t)(bid & 1023) * 256 + threadIdx.x) * 4;
        float4 v = *reinterpret_cast<const float4*>(src + i);
        ushort4 o;
        o.x = f2bf(v.x); o.y = f2bf(v.y); o.z = f2bf(v.z); o.w = f2bf(v.w);
        *reinterpret_cast<ushort4*>(dst + i) = o;
    } else if (bid < 2304) {                // u[row] = Wk[row,:].bq
        const int wave = threadIdx.x >> 6, lane = threadIdx.x & 63;
        const int row = (bid - 2048) * 4 + wave;
        const float* wr = Wk + (size_t)row * DIM;
        float s = 0.f;
#pragma unroll
        for (int p = 0; p < 4; ++p) {
            int col = p * 256 + lane * 4;
            float4 v = *reinterpret_cast<const float4*>(wr + col);
            float4 b = *reinterpret_cast<const float4*>(bq + col);
            s += v.x * b.x + v.y * b.y + v.z * b.z + v.w * b.w;
        }
#pragma unroll
        for (int off = 32; off; off >>= 1) s += __shfl_xor(s, off);
        if (lane == 0) u[row] = s;
    } else {                                // out[b,n] = bv[n]
        int i = (bid - 2304) * 256 + threadIdx.x;
        out[i] = bv[i & (DIM - 1)];
    }
}

// ---------------- 128x128 tile bf16 GEMM (for Mt = Wk Wq^T) ----------------
__device__ __forceinline__ void gemm_bt_tile128(const unsigned short* __restrict__ A,
                                                const unsigned short* __restrict__ Bt,
                                                int K, int m0, int n0, int lda, int ldb,
                                                unsigned short* ldsA, unsigned short* ldsB,
                                                f32x4 acc[4][4]) {
    const int tid  = threadIdx.x;
    const int wave = tid >> 6;
    const int lane = tid & 63;
    const int lrow = lane >> 3;
    const int lcol = lane & 7;
    const int wm = (wave >> 1) * 64;
    const int wn = (wave & 1) * 64;
    const int fr = lane & 15;
    const int fg = lane >> 4;

    for (int k0 = 0; k0 < K; k0 += 64) {
#pragma unroll
        for (int r = 0; r < 4; ++r) {
            int row = r * 32 + wave * 8 + lrow;
            async16(A + (size_t)(m0 + row) * lda + k0 + lcol * 8, ldsA + r * 2048 + wave * 512);
            async16(Bt + (size_t)(n0 + row) * ldb + k0 + lcol * 8, ldsB + r * 2048 + wave * 512);
        }
        __syncthreads();
#pragma unroll
        for (int ks = 0; ks < 2; ++ks) {
            bf16x8 af[4], bfr[4];
#pragma unroll
            for (int mf = 0; mf < 4; ++mf)
                af[mf] = *reinterpret_cast<const bf16x8*>(ldsA + (wm + mf * 16 + fr) * 64 + ks * 32 + fg * 8);
#pragma unroll
            for (int nf = 0; nf < 4; ++nf)
                bfr[nf] = *reinterpret_cast<const bf16x8*>(ldsB + (wn + nf * 16 + fr) * 64 + ks * 32 + fg * 8);
#pragma unroll
            for (int mf = 0; mf < 4; ++mf)
#pragma unroll
                for (int nf = 0; nf < 4; ++nf)
                    acc[mf][nf] = __builtin_amdgcn_mfma_f32_16x16x32_bf16(af[mf], bfr[nf], acc[mf][nf], 0, 0, 0);
        }
        __syncthreads();
    }
}

// ---------------- K1 (fused): blocks 0-63: Mt8 = perm-fp8(64*Wk Wq^T);
//                  blocks 64+: x -> bf16 + perm-fp8, c[row] = scale*x.u ----
__global__ __launch_bounds__(256) void k_cvtx_mm(const float* __restrict__ x,
                                                 const float* __restrict__ u,
                                                 const unsigned short* __restrict__ wkb,
                                                 const unsigned short* __restrict__ wqb,
                                                 unsigned short* __restrict__ xb,
                                                 unsigned char* __restrict__ xb8,
                                                 float* __restrict__ c,
                                                 unsigned char* __restrict__ Mt8) {
    __shared__ unsigned short ldsA[8192];
    __shared__ unsigned short ldsB[8192];
    const int bid = blockIdx.x;
    if (bid < 64) {
        int m0 = (bid & 7) * 128, n0 = (bid >> 3) * 128;
        f32x4 acc[4][4] = {};
        gemm_bt_tile128(wkb, wqb, DIM, m0, n0, DIM, DIM, ldsA, ldsB, acc);
        const int lane = threadIdx.x & 63, wave = threadIdx.x >> 6;
        const int wm = (wave >> 1) * 64, wn = (wave & 1) * 64;
        const int fr = lane & 15, fg = lane >> 4;
#pragma unroll
        for (int nf = 0; nf < 4; ++nf) {
            int n = n0 + wn + nf * 16 + fr;
            int pn = perm128(n);
#pragma unroll
            for (int mf = 0; mf < 4; ++mf) {
                int r0 = m0 + wm + mf * 16 + fg * 4;
                int pk01 = __builtin_amdgcn_cvt_pk_fp8_f32(acc[mf][nf][0] * 64.f, acc[mf][nf][1] * 64.f, 0, false);
                int pk23 = __builtin_amdgcn_cvt_pk_fp8_f32(acc[mf][nf][2] * 64.f, acc[mf][nf][3] * 64.f, 0, false);
                Mt8[(size_t)(r0 + 0) * DIM + pn] = (unsigned char)(pk01 & 0xff);
                Mt8[(size_t)(r0 + 1) * DIM + pn] = (unsigned char)((pk01 >> 8) & 0xff);
                Mt8[(size_t)(r0 + 2) * DIM + pn] = (unsigned char)(pk23 & 0xff);
                Mt8[(size_t)(r0 + 3) * DIM + pn] = (unsigned char)((pk23 >> 8) & 0xff);
            }
        }
    } else {
        float* red = (float*)ldsA;
        const int row = bid - 64, tid = threadIdx.x;
        size_t i = (size_t)row * DIM + tid * 4;
        float4 v = *reinterpret_cast<const float4*>(x + i);
        ushort4 o;
        o.x = f2bf(v.x); o.y = f2bf(v.y); o.z = f2bf(v.z); o.w = f2bf(v.w);
        *reinterpret_cast<ushort4*>(xb + i) = o;
        int pk = __builtin_amdgcn_cvt_pk_fp8_f32(v.x, v.y, 0, false);
        pk = __builtin_amdgcn_cvt_pk_fp8_f32(v.z, v.w, pk, true);
        int pp = perm128(tid * 4);   // 4 elems stay in one 8B chunk
        *reinterpret_cast<unsigned int*>(xb8 + (size_t)row * DIM + pp) = (unsigned int)pk;
        float4 uv = *reinterpret_cast<const float4*>(u + tid * 4);
        float s = v.x * uv.x + v.y * uv.y + v.z * uv.z + v.w * uv.w;
#pragma unroll
        for (int off = 32; off; off >>= 1) s += __shfl_xor(s, off);
        if ((tid & 63) == 0) red[tid >> 6] = s;
        __syncthreads();
        if (tid == 0) c[row] = 0.03125f * (red[0] + red[1] + red[2] + red[3]);
    }
}

// ---------------------------------------------------------------------------
// 256x256 fp8 GEMM core. K = 1024, BK = 128 fp8 (permuted rows). Fragment
// reads = forced ds_read_b128 at 16B-slot XOR-swizzled addrs; two reads
// concatenate into the v8i32 operand of the K=128 MX-scaled MFMA.
// 8 K-tiles, 4 iters, 1 barrier/phase, vmcnt(4) at phases 4/8.
// ---------------------------------------------------------------------------

#define STAGE8(gbase, ld, dstoff)                                         \
    do {                                                                  \
        async16b((gbase), ldsw + (dstoff));                               \
        async16b((gbase) + 8 * (size_t)(ld), ldsw + (dstoff) + 1024);     \
    } while (0)
#define STAGE8_A(buf, half, kt) STAGE8(gA + (size_t)((half) * 128) * lda + (kt) * 128, lda, (buf) * 32768 + (half) * 16384)
#define STAGE8_B(buf, half, kt) STAGE8(gB + (size_t)((half) * 128) * ldb + (kt) * 128, ldb, 65536 + (buf) * 32768 + (half) * 16384)

#define FRAG8(base_b, row, colb) \
    ds_read128(lds, (base_b) + (row) * 128 + ((colb) ^ (((row) & 7) << 4)))

#define READ8_A(dbuf, mh)                                                     \
    _Pragma("unroll") for (int m2 = 0; m2 < 4; ++m2) {                        \
        int arow = ((mh) * 4 + m2) * 16 + fr;                                 \
        i32x4 lo = FRAG8((dbuf) * 32768 + wr * 16384, arow, fg * 32);         \
        i32x4 hi = FRAG8((dbuf) * 32768 + wr * 16384, arow, fg * 32 + 16);    \
        afc[(mh) * 4 + m2] =                                                  \
            __builtin_shufflevector(lo, hi, 0, 1, 2, 3, 4, 5, 6, 7);          \
    }
#define READ8_B(dbuf, nh)                                                     \
    _Pragma("unroll") for (int n2 = 0; n2 < 2; ++n2) {                        \
        int brow = (wc & 1) * 64 + ((nh) * 2 + n2) * 16 + fr;                 \
        i32x4 lo = FRAG8(65536 + (dbuf) * 32768 + (wc >> 1) * 16384, brow,    \
                         fg * 32);                                            \
        i32x4 hi = FRAG8(65536 + (dbuf) * 32768 + (wc >> 1) * 16384, brow,    \
                         fg * 32 + 16);                                       \
        bfc[nh][n2] =                                                         \
            __builtin_shufflevector(lo, hi, 0, 1, 2, 3, 4, 5, 6, 7);          \
    }

#define VM4 asm volatile("s_waitcnt vmcnt(4)" ::: "memory")

#define PHASE8(mh, nh, STG, VM, PF)                                           \
    do {                                                                      \
        STG;                                                                  \
        VM;                                                                   \
        asm volatile("s_barrier" ::: "memory");                               \
        asm volatile("s_waitcnt lgkmcnt(0)" ::: "memory");                    \
        __builtin_amdgcn_sched_barrier(0);                                    \
        PF;                                                                   \
        __builtin_amdgcn_sched_barrier(0);                                    \
        __builtin_amdgcn_s_setprio(1);                                        \
        _Pragma("unroll") for (int m2 = 0; m2 < 4; ++m2)                      \
        _Pragma("unroll") for (int n2 = 0; n2 < 2; ++n2) {                    \
            f32x4& a = acc[(mh) * 4 + m2][(nh) * 2 + n2];                     \
            a = mfma128(afc[(mh) * 4 + m2], bfc[nh][n2], a);                  \
        }                                                                     \
        __builtin_amdgcn_s_setprio(0);                                        \
    } while (0)

__device__ __forceinline__ void gemm256_fp8(const unsigned char* __restrict__ A,
                                            const unsigned char* __restrict__ Bt,
                                            int lda, int ldb, int m0, int n0,
                                            unsigned char* lds, f32x4 (&acc)[8][4]) {
    constexpr int NKT = 1024 / 128;  // 8 K-tiles
    constexpr int NIT = NKT / 2;     // 4 iterations
    const int tid = threadIdx.x;
    const int w = tid >> 6, lane = tid & 63;
    const int wr = w >> 2, wc = w & 3;
    const int fr = lane & 15, fg = lane >> 4;
    const int r8 = lane >> 3, slot = (lane & 7) ^ r8;

    const unsigned char* gA = A + (size_t)(m0 + w * 16 + r8) * lda + slot * 16;
    const unsigned char* gB = Bt + (size_t)(n0 + w * 16 + r8) * ldb + slot * 16;
    unsigned char* ldsw = lds + w * 2048;

    i32x8 afc[8];
    i32x8 bfc[2][2];

    STAGE8_A(0, 0, 0); STAGE8_A(0, 1, 0); STAGE8_B(0, 0, 0); STAGE8_B(0, 1, 0);
    STAGE8_A(1, 0, 1); STAGE8_A(1, 1, 1);
    VM4;
    asm volatile("s_barrier" ::: "memory");
    READ8_A(0, 0); READ8_B(0, 0);

    for (int it = 0; it < NIT; ++it) {
        const int t1 = 2 * it + 1;
        const int ka = (2 * it + 2) & (NKT - 1);
        const int kb = (2 * it + 3) & (NKT - 1);
        PHASE8(0, 0, STAGE8_B(1, 0, t1), , READ8_A(0, 1));
        PHASE8(1, 0, STAGE8_B(1, 1, t1), , READ8_B(0, 1));
        PHASE8(0, 1, STAGE8_A(0, 0, ka), , );
        PHASE8(1, 1, STAGE8_A(0, 1, ka), VM4, READ8_A(1, 0); READ8_B(1, 0));
        PHASE8(0, 0, STAGE8_B(0, 0, ka), , READ8_A(1, 1));
        PHASE8(1, 0, STAGE8_B(0, 1, ka), , READ8_B(1, 1));
        PHASE8(0, 1, STAGE8_A(1, 0, kb), , );
        PHASE8(1, 1, STAGE8_A(1, 1, kb), VM4, READ8_A(0, 0); READ8_B(0, 0));
    }
    asm volatile("s_waitcnt vmcnt(0) lgkmcnt(0)" ::: "memory");
}

// ---------------- K2: y8 = permuted fp8(8*y)  (A=xb8, Bt=Mt8) ----------------
__global__ __launch_bounds__(512, 1) void k_proj_y(const unsigned char* __restrict__ xb8,
                                                   const unsigned char* __restrict__ Mt8,
                                                   unsigned char* __restrict__ y8) {
    __shared__ unsigned char lds[131072];   // 128 KiB -> 1 block/CU regardless
    const int f = blockIdx.x;
    const int m_hi = f & 7, j = f >> 3;
    const int n_t = j & 3, m_lo = j >> 2;
    const int m0 = (m_hi * 8 + m_lo) * 256, n0 = n_t * 256;

    f32x4 acc[8][4] = {};
    gemm256_fp8(xb8, Mt8, DIM, DIM, m0, n0, lds, acc);

    const int tid = threadIdx.x, w = tid >> 6, lane = tid & 63;
    const int wr = w >> 2, wc = w & 3, fr = lane & 15, fg = lane >> 4;
#pragma unroll
    for (int nf = 0; nf < 4; ++nf) {
        int n = n0 + wc * 64 + nf * 16 + fr;
        int pn = perm128(n);
#pragma unroll
        for (int mf = 0; mf < 8; ++mf) {
            int r0 = m0 + wr * 128 + mf * 16 + fg * 4;
            int pk01 = __builtin_amdgcn_cvt_pk_fp8_f32(acc[mf][nf][0] * 0.125f, acc[mf][nf][1] * 0.125f, 0, false);
            int pk23 = __builtin_amdgcn_cvt_pk_fp8_f32(acc[mf][nf][2] * 0.125f, acc[mf][nf][3] * 0.125f, 0, false);
            y8[(size_t)(r0 + 0) * DIM + pn] = (unsigned char)(pk01 & 0xff);
            y8[(size_t)(r0 + 1) * DIM + pn] = (unsigned char)((pk01 >> 8) & 0xff);
            y8[(size_t)(r0 + 2) * DIM + pn] = (unsigned char)(pk23 & 0xff);
            y8[(size_t)(r0 + 3) * DIM + pn] = (unsigned char)((pk23 >> 8) & 0xff);
        }
    }
}

// ---------------- K3: PT[t][s] = fp8(exp(acc*scl/8 + c[t])), ell[s] = rowsum ----------------
__global__ __launch_bounds__(512, 1) void k_scores(const unsigned char* __restrict__ y8,
                                                   const unsigned char* __restrict__ xb8,
                                                   const float* __restrict__ c,
                                                   unsigned char* __restrict__ PT,
                                                   float* __restrict__ ell) {
    __shared__ unsigned char lds[131072];
    const int f = blockIdx.x;
    const int b = f & 7, j = f >> 3;
    const int mt = j & 7, nt = j >> 3;
    const unsigned char* q = y8 + (size_t)b * SEQ * DIM;
    const unsigned char* k = xb8 + (size_t)b * SEQ * DIM;
    const int m0 = mt * 256, n0 = nt * 256;

    f32x4 acc[8][4] = {};
    gemm256_fp8(q, k, DIM, DIM, m0, n0, lds, acc);

    const float scl8 = 0.00390625f;  // (1/32)/8 : y8 carries 8x
    const int tid = threadIdx.x, w = tid >> 6, lane = tid & 63;
    const int wr = w >> 2, wc = w & 3, fr = lane & 15, fg = lane >> 4;
    unsigned char* Pb = PT + (size_t)b * SEQ * SEQ;
    float cv[4];
#pragma unroll
    for (int nf = 0; nf < 4; ++nf)
        cv[nf] = c[(size_t)b * SEQ + n0 + wc * 64 + nf * 16 + fr];
#pragma unroll
    for (int mf = 0; mf < 8; ++mf) {
        const int sbase = m0 + wr * 128 + mf * 16 + fg * 4;
        float rs[4] = {0.f, 0.f, 0.f, 0.f};
#pragma unroll
        for (int nf = 0; nf < 4; ++nf) {
            int t = n0 + wc * 64 + nf * 16 + fr;
            float p0 = __expf(fmaf(acc[mf][nf][0], scl8, cv[nf]));
            float p1 = __expf(fmaf(acc[mf][nf][1], scl8, cv[nf]));
            float p2 = __expf(fmaf(acc[mf][nf][2], scl8, cv[nf]));
            float p3 = __expf(fmaf(acc[mf][nf][3], scl8, cv[nf]));
            int pk = __builtin_amdgcn_cvt_pk_fp8_f32(p0, p1, 0, false);
            pk = __builtin_amdgcn_cvt_pk_fp8_f32(p2, p3, pk, true);
            *reinterpret_cast<unsigned int*>(Pb + (size_t)t * SEQ + sbase) = (unsigned int)pk;
            f32x2 d01 = __builtin_amdgcn_cvt_pk_f32_fp8(pk, false);
            f32x2 d23 = __builtin_amdgcn_cvt_pk_f32_fp8(pk, true);
            rs[0] += d01[0]; rs[1] += d01[1]; rs[2] += d23[0]; rs[3] += d23[1];
        }
#pragma unroll
        for (int j2 = 0; j2 < 4; ++j2) {
            float r = rs[j2];
            r += __shfl_xor(r, 1);
            r += __shfl_xor(r, 2);
            r += __shfl_xor(r, 4);
            r += __shfl_xor(r, 8);
            if (fr == 0) atomicAdd(&ell[b * SEQ + sbase + j2], r);
        }
    }
}

// ---------------- K4: w[t] = sum_s PT[t][s] / ell[s] ----------------
__global__ __launch_bounds__(256) void k_colsum(const unsigned char* __restrict__ PT,
                                                const float* __restrict__ ell,
                                                float* __restrict__ w) {
    __shared__ float rel[512];
    const int b = blockIdx.z;
    const int s0 = blockIdx.x * 512;
    const int t = blockIdx.y * 256 + threadIdx.x;
    {
        int i = threadIdx.x;
        rel[i]       = 1.0f / ell[b * SEQ + s0 + i];
        rel[i + 256] = 1.0f / ell[b * SEQ + s0 + 256 + i];
    }
    __syncthreads();
    const unsigned char* Pt = PT + (size_t)b * SEQ * SEQ + (size_t)t * SEQ + s0;
    float a = 0.f;
    for (int i = 0; i < 512; i += 8) {
        uint2 pv = *reinterpret_cast<const uint2*>(Pt + i);
        f32x2 d0 = __builtin_amdgcn_cvt_pk_f32_fp8((int)pv.x, false);
        f32x2 d1 = __builtin_amdgcn_cvt_pk_f32_fp8((int)pv.x, true);
        f32x2 d2 = __builtin_amdgcn_cvt_pk_f32_fp8((int)pv.y, false);
        f32x2 d3 = __builtin_amdgcn_cvt_pk_f32_fp8((int)pv.y, true);
        a += d0[0] * rel[i]     + d0[1] * rel[i + 1] + d1[0] * rel[i + 2] + d1[1] * rel[i + 3];
        a += d2[0] * rel[i + 4] + d2[1] * rel[i + 5] + d3[0] * rel[i + 6] + d3[1] * rel[i + 7];
    }
    atomicAdd(&w[b * SEQ + t], a);
}

// ---------------- K5: g[b,d] = (1/S) sum_t w[b,t] * xb[b,t,d]  (bf16 x) ----------------
__global__ __launch_bounds__(256) void k_accx(const float* __restrict__ w,
                                              const unsigned short* __restrict__ xb,
                                              float* __restrict__ g) {
    const int b = blockIdx.y;
    const int t0 = blockIdx.x * 64 + (threadIdx.x >> 7) * 32;
    const int d8 = (threadIdx.x & 127) * 8;
    const unsigned short* xbb = xb + (size_t)b * SEQ * DIM;
    const float* wb = w + b * SEQ;
    float a[8] = {};
    for (int i = 0; i < 32; ++i) {
        int t = t0 + i;
        float wt = wb[t];
        u16x8 v = *reinterpret_cast<const u16x8*>(xbb + (size_t)t * DIM + d8);
#pragma unroll
        for (int j = 0; j < 8; ++j) a[j] += wt * bf2f(v[j]);
    }
#pragma unroll
    for (int j = 0; j < 8; ++j)
        atomicAdd(&g[b * DIM + d8 + j], a[j] * (1.0f / (float)SEQ));
}

// ---------------- K6: out[b,n] += sum_{d in chunk} g[b,d] * Wv[d,n] ----------------
__global__ __launch_bounds__(256) void k_out2(const float* __restrict__ g,
                                              const float* __restrict__ Wv,
                                              float* __restrict__ out) {
    int b = blockIdx.y;
    int n = blockIdx.x * 256 + threadIdx.x;
    int d0 = blockIdx.z * 64;
    const float* gb = g + b * DIM;
    float acc = 0.f;
#pragma unroll
    for (int d = 0; d < 64; ++d)
        acc += gb[d0 + d] * Wv[(size_t)(d0 + d) * DIM + n];
    atomicAdd(&out[b * DIM + n], acc);
}

extern "C" void kernel_launch(void* const* d_in, const int* in_sizes, int n_in,
                              void* d_out, int out_size, void* d_ws, size_t ws_size,
                              hipStream_t stream) {
    const float* x  = (const float*)d_in[0];
    const float* Wq = (const float*)d_in[1];
    const float* bq = (const float*)d_in[2];
    const float* Wk = (const float*)d_in[3];
    const float* bk = (const float*)d_in[4];   // unused (softmax-invariant)
    const float* Wv = (const float*)d_in[5];
    const float* bv = (const float*)d_in[6];
    float* out = (float*)d_out;
    (void)bk;

    char* ws = (char*)d_ws;
    unsigned short* xb  = (unsigned short*)(ws);                    //  33,554,432
    unsigned short* wkb = (unsigned short*)(ws + 33554432ull);      //   2,097,152
    unsigned short* wqb = (unsigned short*)(ws + 35651584ull);      //   2,097,152
    unsigned char*  Mt8 = (unsigned char*)(ws + 37748736ull);       //   1,048,576
    unsigned char*  xb8 = (unsigned char*)(ws + 38797312ull);       //  16,777,216
    unsigned char*  y8  = (unsigned char*)(ws + 55574528ull);       //  16,777,216
    unsigned char*  PT  = (unsigned char*)(ws + 72351744ull);       //  33,554,432
    float*          ell = (float*)(ws + 105906176ull);              //      65,536
    float*          w   = (float*)(ws + 105971712ull);              //      65,536
    float*          g   = (float*)(ws + 106037248ull);              //      32,768
    float*          c   = (float*)(ws + 106070016ull);              //      65,536
    float*          u   = (float*)(ws + 106135552ull);              //       4,096

    // single memset: ell + w + g contiguous (163,840 bytes)
    hipMemsetAsync(ell, 0, 163840, stream);

    k_prep<<<dim3(2336), 256, 0, stream>>>(Wk, Wq, bq, bv, wkb, wqb, u, out);
    k_cvtx_mm<<<dim3(64 + MTOT), 256, 0, stream>>>(x, u, wkb, wqb, xb, xb8, c, Mt8);
    k_proj_y<<<dim3(256), 512, 0, stream>>>(xb8, Mt8, y8);
    k_scores<<<dim3(512), 512, 0, stream>>>(y8, xb8, c, PT, ell);
    k_colsum<<<dim3(SEQ / 512, SEQ / 256, NB), 256, 0, stream>>>(PT, ell, w);
    k_accx<<<dim3(SEQ / 64, NB), 256, 0, stream>>>(w, xb, g);
    k_out2<<<dim3(DIM / 256, NB, 16), 256, 0, stream>>>(g, Wv, out);
}

// Round 16
// 188.746 us; speedup vs baseline: 1.0012x; 1.0012x over previous
//
#include <hip/hip_runtime.h>

// ---------------------------------------------------------------------------
// AttentionFuse: out[b,d] = mean_s( softmax((x Wq + bq)(x Wk + bk)^T / 32) @ (x Wv + bv) )
// Algebra:
//   mean_s(attn @ V) = sum_t a[t] V[t,:]  =>  out = (a^T x) Wv + bv   (V GEMM gone)
//   S = x (Wq Wk^T) x^T  =>  y = x Mt^T, Mt = Wk Wq^T (2.1 GF)  =>  S = y x^T
//   bias: P[s,t] = exp(scale*S + c[t]),  c[t] = scale * x[t].u,  u = Wk bq
// R16: MX fp8 MFMA kept; GEMM kernels pinned with amdgpu_waves_per_eu(2,2).
//   R15 showed launch_bounds(512,1) produced an identical binary: the second
//   arg is only a MINIMUM; the compiler's occupancy heuristic chose 128 VGPRs
//   (targeting 4 waves/EU, blind to the 128KiB-LDS 1-block/CU cap) and
//   spilled the v8i32 MFMA operands (~170 VGPR demand). waves_per_eu(2,2)
//   pins exactly 2 waves/EU -> 256-VGPR budget at unchanged occupancy.
// ---------------------------------------------------------------------------

using bf16x8 = __attribute__((ext_vector_type(8))) __bf16;
using u16x8  = __attribute__((ext_vector_type(8))) unsigned short;
using f32x4  = __attribute__((ext_vector_type(4))) float;
using f32x2  = __attribute__((ext_vector_type(2))) float;
using i32x4  = __attribute__((ext_vector_type(4))) int;
using i32x8  = __attribute__((ext_vector_type(8))) int;

#define NB 8
#define SEQ 2048
#define DIM 1024
#define MTOT (NB * SEQ)          // 16384

__device__ __forceinline__ unsigned short f2bf(float f) {
    unsigned int u = __float_as_uint(f);
    u = u + 0x7FFFu + ((u >> 16) & 1u);   // RNE
    return (unsigned short)(u >> 16);
}
__device__ __forceinline__ float bf2f(unsigned short h) {
    return __uint_as_float(((unsigned int)h) << 16);
}
// byte position of element k within a permuted 128-elem fp8 K-block
__device__ __forceinline__ int perm128(int n) {
    return (n & ~127) + ((n >> 3) & 3) * 32 + ((n & 127) >> 5) * 8 + (n & 7);
}

__device__ __forceinline__ void async16(const unsigned short* g, unsigned short* l) {
    __builtin_amdgcn_global_load_lds(
        (const __attribute__((address_space(1))) void*)g,
        (__attribute__((address_space(3))) void*)l, 16, 0, 0);
}
__device__ __forceinline__ void async16b(const unsigned char* g, unsigned char* l) {
    __builtin_amdgcn_global_load_lds(
        (const __attribute__((address_space(1))) void*)g,
        (__attribute__((address_space(3))) void*)l, 16, 0, 0);
}
// MX-scaled fp8 MFMA, K=128, unit scales (E8M0 0x7F = 2^0); fmt 0 = e4m3
__device__ __forceinline__ f32x4 mfma128(i32x8 a, i32x8 b, f32x4 c) {
    return __builtin_amdgcn_mfma_scale_f32_16x16x128_f8f6f4(
        a, b, c, 0, 0, 0, 0x7f7f7f7f, 0, 0x7f7f7f7f);
}
// forced 16B LDS read (one ds_read_b128)
__device__ __forceinline__ i32x4 ds_read128(const unsigned char* base, int off) {
    unsigned addr = (unsigned)(size_t)(
        (const __attribute__((address_space(3))) unsigned char*)base + off);
    i32x4 r;
    asm volatile("ds_read_b128 %0, %1" : "=v"(r) : "v"(addr));
    return r;
}

// ---------------- K0 (merged prep): cvt_w x2, u = Wk bq, out = bv ----------------
__global__ __launch_bounds__(256) void k_prep(const float* __restrict__ Wk,
                                              const float* __restrict__ Wq,
                                              const float* __restrict__ bq,
                                              const float* __restrict__ bv,
                                              unsigned short* __restrict__ wkb,
                                              unsigned short* __restrict__ wqb,
                                              float* __restrict__ u,
                                              float* __restrict__ out) {
    const int bid = blockIdx.x;
    if (bid < 2048) {                       // Wk,Wq fp32 -> bf16
        const float* src = (bid >= 1024) ? Wq : Wk;
        unsigned short* dst = (bid >= 1024) ? wqb : wkb;
        size_t i = ((size_t)(bid & 1023) * 256 + threadIdx.x) * 4;
        float4 v = *reinterpret_cast<const float4*>(src + i);
        ushort4 o;
        o.x = f2bf(v.x); o.y = f2bf(v.y); o.z = f2bf(v.z); o.w = f2bf(v.w);
        *reinterpret_cast<ushort4*>(dst + i) = o;
    } else if (bid < 2304) {                // u[row] = Wk[row,:].bq
        const int wave = threadIdx.x >> 6, lane = threadIdx.x & 63;
        const int row = (bid - 2048) * 4 + wave;
        const float* wr = Wk + (size_t)row * DIM;
        float s = 0.f;
#pragma unroll
        for (int p = 0; p < 4; ++p) {
            int col = p * 256 + lane * 4;
            float4 v = *reinterpret_cast<const float4*>(wr + col);
            float4 b = *reinterpret_cast<const float4*>(bq + col);
            s += v.x * b.x + v.y * b.y + v.z * b.z + v.w * b.w;
        }
#pragma unroll
        for (int off = 32; off; off >>= 1) s += __shfl_xor(s, off);
        if (lane == 0) u[row] = s;
    } else {                                // out[b,n] = bv[n]
        int i = (bid - 2304) * 256 + threadIdx.x;
        out[i] = bv[i & (DIM - 1)];
    }
}

// ---------------- 128x128 tile bf16 GEMM (for Mt = Wk Wq^T) ----------------
__device__ __forceinline__ void gemm_bt_tile128(const unsigned short* __restrict__ A,
                                                const unsigned short* __restrict__ Bt,
                                                int K, int m0, int n0, int lda, int ldb,
                                                unsigned short* ldsA, unsigned short* ldsB,
                                                f32x4 acc[4][4]) {
    const int tid  = threadIdx.x;
    const int wave = tid >> 6;
    const int lane = tid & 63;
    const int lrow = lane >> 3;
    const int lcol = lane & 7;
    const int wm = (wave >> 1) * 64;
    const int wn = (wave & 1) * 64;
    const int fr = lane & 15;
    const int fg = lane >> 4;

    for (int k0 = 0; k0 < K; k0 += 64) {
#pragma unroll
        for (int r = 0; r < 4; ++r) {
            int row = r * 32 + wave * 8 + lrow;
            async16(A + (size_t)(m0 + row) * lda + k0 + lcol * 8, ldsA + r * 2048 + wave * 512);
            async16(Bt + (size_t)(n0 + row) * ldb + k0 + lcol * 8, ldsB + r * 2048 + wave * 512);
        }
        __syncthreads();
#pragma unroll
        for (int ks = 0; ks < 2; ++ks) {
            bf16x8 af[4], bfr[4];
#pragma unroll
            for (int mf = 0; mf < 4; ++mf)
                af[mf] = *reinterpret_cast<const bf16x8*>(ldsA + (wm + mf * 16 + fr) * 64 + ks * 32 + fg * 8);
#pragma unroll
            for (int nf = 0; nf < 4; ++nf)
                bfr[nf] = *reinterpret_cast<const bf16x8*>(ldsB + (wn + nf * 16 + fr) * 64 + ks * 32 + fg * 8);
#pragma unroll
            for (int mf = 0; mf < 4; ++mf)
#pragma unroll
                for (int nf = 0; nf < 4; ++nf)
                    acc[mf][nf] = __builtin_amdgcn_mfma_f32_16x16x32_bf16(af[mf], bfr[nf], acc[mf][nf], 0, 0, 0);
        }
        __syncthreads();
    }
}

// ---------------- K1 (fused): blocks 0-63: Mt8 = perm-fp8(64*Wk Wq^T);
//                  blocks 64+: x -> bf16 + perm-fp8, c[row] = scale*x.u ----
__global__ __launch_bounds__(256) void k_cvtx_mm(const float* __restrict__ x,
                                                 const float* __restrict__ u,
                                                 const unsigned short* __restrict__ wkb,
                                                 const unsigned short* __restrict__ wqb,
                                                 unsigned short* __restrict__ xb,
                                                 unsigned char* __restrict__ xb8,
                                                 float* __restrict__ c,
                                                 unsigned char* __restrict__ Mt8) {
    __shared__ unsigned short ldsA[8192];
    __shared__ unsigned short ldsB[8192];
    const int bid = blockIdx.x;
    if (bid < 64) {
        int m0 = (bid & 7) * 128, n0 = (bid >> 3) * 128;
        f32x4 acc[4][4] = {};
        gemm_bt_tile128(wkb, wqb, DIM, m0, n0, DIM, DIM, ldsA, ldsB, acc);
        const int lane = threadIdx.x & 63, wave = threadIdx.x >> 6;
        const int wm = (wave >> 1) * 64, wn = (wave & 1) * 64;
        const int fr = lane & 15, fg = lane >> 4;
#pragma unroll
        for (int nf = 0; nf < 4; ++nf) {
            int n = n0 + wn + nf * 16 + fr;
            int pn = perm128(n);
#pragma unroll
            for (int mf = 0; mf < 4; ++mf) {
                int r0 = m0 + wm + mf * 16 + fg * 4;
                int pk01 = __builtin_amdgcn_cvt_pk_fp8_f32(acc[mf][nf][0] * 64.f, acc[mf][nf][1] * 64.f, 0, false);
                int pk23 = __builtin_amdgcn_cvt_pk_fp8_f32(acc[mf][nf][2] * 64.f, acc[mf][nf][3] * 64.f, 0, false);
                Mt8[(size_t)(r0 + 0) * DIM + pn] = (unsigned char)(pk01 & 0xff);
                Mt8[(size_t)(r0 + 1) * DIM + pn] = (unsigned char)((pk01 >> 8) & 0xff);
                Mt8[(size_t)(r0 + 2) * DIM + pn] = (unsigned char)(pk23 & 0xff);
                Mt8[(size_t)(r0 + 3) * DIM + pn] = (unsigned char)((pk23 >> 8) & 0xff);
            }
        }
    } else {
        float* red = (float*)ldsA;
        const int row = bid - 64, tid = threadIdx.x;
        size_t i = (size_t)row * DIM + tid * 4;
        float4 v = *reinterpret_cast<const float4*>(x + i);
        ushort4 o;
        o.x = f2bf(v.x); o.y = f2bf(v.y); o.z = f2bf(v.z); o.w = f2bf(v.w);
        *reinterpret_cast<ushort4*>(xb + i) = o;
        int pk = __builtin_amdgcn_cvt_pk_fp8_f32(v.x, v.y, 0, false);
        pk = __builtin_amdgcn_cvt_pk_fp8_f32(v.z, v.w, pk, true);
        int pp = perm128(tid * 4);   // 4 elems stay in one 8B chunk
        *reinterpret_cast<unsigned int*>(xb8 + (size_t)row * DIM + pp) = (unsigned int)pk;
        float4 uv = *reinterpret_cast<const float4*>(u + tid * 4);
        float s = v.x * uv.x + v.y * uv.y + v.z * uv.z + v.w * uv.w;
#pragma unroll
        for (int off = 32; off; off >>= 1) s += __shfl_xor(s, off);
        if ((tid & 63) == 0) red[tid >> 6] = s;
        __syncthreads();
        if (tid == 0) c[row] = 0.03125f * (red[0] + red[1] + red[2] + red[3]);
    }
}

// ---------------------------------------------------------------------------
// 256x256 fp8 GEMM core. K = 1024, BK = 128 fp8 (permuted rows). Fragment
// reads = forced ds_read_b128 at 16B-slot XOR-swizzled addrs; two reads
// concatenate into the v8i32 operand of the K=128 MX-scaled MFMA.
// 8 K-tiles, 4 iters, 1 barrier/phase, vmcnt(4) at phases 4/8.
// ---------------------------------------------------------------------------

#define STAGE8(gbase, ld, dstoff)                                         \
    do {                                                                  \
        async16b((gbase), ldsw + (dstoff));                               \
        async16b((gbase) + 8 * (size_t)(ld), ldsw + (dstoff) + 1024);     \
    } while (0)
#define STAGE8_A(buf, half, kt) STAGE8(gA + (size_t)((half) * 128) * lda + (kt) * 128, lda, (buf) * 32768 + (half) * 16384)
#define STAGE8_B(buf, half, kt) STAGE8(gB + (size_t)((half) * 128) * ldb + (kt) * 128, ldb, 65536 + (buf) * 32768 + (half) * 16384)

#define FRAG8(base_b, row, colb) \
    ds_read128(lds, (base_b) + (row) * 128 + ((colb) ^ (((row) & 7) << 4)))

#define READ8_A(dbuf, mh)                                                     \
    _Pragma("unroll") for (int m2 = 0; m2 < 4; ++m2) {                        \
        int arow = ((mh) * 4 + m2) * 16 + fr;                                 \
        i32x4 lo = FRAG8((dbuf) * 32768 + wr * 16384, arow, fg * 32);         \
        i32x4 hi = FRAG8((dbuf) * 32768 + wr * 16384, arow, fg * 32 + 16);    \
        afc[(mh) * 4 + m2] =                                                  \
            __builtin_shufflevector(lo, hi, 0, 1, 2, 3, 4, 5, 6, 7);          \
    }
#define READ8_B(dbuf, nh)                                                     \
    _Pragma("unroll") for (int n2 = 0; n2 < 2; ++n2) {                        \
        int brow = (wc & 1) * 64 + ((nh) * 2 + n2) * 16 + fr;                 \
        i32x4 lo = FRAG8(65536 + (dbuf) * 32768 + (wc >> 1) * 16384, brow,    \
                         fg * 32);                                            \
        i32x4 hi = FRAG8(65536 + (dbuf) * 32768 + (wc >> 1) * 16384, brow,    \
                         fg * 32 + 16);                                       \
        bfc[nh][n2] =                                                         \
            __builtin_shufflevector(lo, hi, 0, 1, 2, 3, 4, 5, 6, 7);          \
    }

#define VM4 asm volatile("s_waitcnt vmcnt(4)" ::: "memory")

#define PHASE8(mh, nh, STG, VM, PF)                                           \
    do {                                                                      \
        STG;                                                                  \
        VM;                                                                   \
        asm volatile("s_barrier" ::: "memory");                               \
        asm volatile("s_waitcnt lgkmcnt(0)" ::: "memory");                    \
        __builtin_amdgcn_sched_barrier(0);                                    \
        PF;                                                                   \
        __builtin_amdgcn_sched_barrier(0);                                    \
        __builtin_amdgcn_s_setprio(1);                                        \
        _Pragma("unroll") for (int m2 = 0; m2 < 4; ++m2)                      \
        _Pragma("unroll") for (int n2 = 0; n2 < 2; ++n2) {                    \
            f32x4& a = acc[(mh) * 4 + m2][(nh) * 2 + n2];                     \
            a = mfma128(afc[(mh) * 4 + m2], bfc[nh][n2], a);                  \
        }                                                                     \
        __builtin_amdgcn_s_setprio(0);                                        \
    } while (0)

__device__ __forceinline__ void gemm256_fp8(const unsigned char* __restrict__ A,
                                            const unsigned char* __restrict__ Bt,
                                            int lda, int ldb, int m0, int n0,
                                            unsigned char* lds, f32x4 (&acc)[8][4]) {
    constexpr int NKT = 1024 / 128;  // 8 K-tiles
    constexpr int NIT = NKT / 2;     // 4 iterations
    const int tid = threadIdx.x;
    const int w = tid >> 6, lane = tid & 63;
    const int wr = w >> 2, wc = w & 3;
    const int fr = lane & 15, fg = lane >> 4;
    const int r8 = lane >> 3, slot = (lane & 7) ^ r8;

    const unsigned char* gA = A + (size_t)(m0 + w * 16 + r8) * lda + slot * 16;
    const unsigned char* gB = Bt + (size_t)(n0 + w * 16 + r8) * ldb + slot * 16;
    unsigned char* ldsw = lds + w * 2048;

    i32x8 afc[8];
    i32x8 bfc[2][2];

    STAGE8_A(0, 0, 0); STAGE8_A(0, 1, 0); STAGE8_B(0, 0, 0); STAGE8_B(0, 1, 0);
    STAGE8_A(1, 0, 1); STAGE8_A(1, 1, 1);
    VM4;
    asm volatile("s_barrier" ::: "memory");
    READ8_A(0, 0); READ8_B(0, 0);

    for (int it = 0; it < NIT; ++it) {
        const int t1 = 2 * it + 1;
        const int ka = (2 * it + 2) & (NKT - 1);
        const int kb = (2 * it + 3) & (NKT - 1);
        PHASE8(0, 0, STAGE8_B(1, 0, t1), , READ8_A(0, 1));
        PHASE8(1, 0, STAGE8_B(1, 1, t1), , READ8_B(0, 1));
        PHASE8(0, 1, STAGE8_A(0, 0, ka), , );
        PHASE8(1, 1, STAGE8_A(0, 1, ka), VM4, READ8_A(1, 0); READ8_B(1, 0));
        PHASE8(0, 0, STAGE8_B(0, 0, ka), , READ8_A(1, 1));
        PHASE8(1, 0, STAGE8_B(0, 1, ka), , READ8_B(1, 1));
        PHASE8(0, 1, STAGE8_A(1, 0, kb), , );
        PHASE8(1, 1, STAGE8_A(1, 1, kb), VM4, READ8_A(0, 0); READ8_B(0, 0));
    }
    asm volatile("s_waitcnt vmcnt(0) lgkmcnt(0)" ::: "memory");
}

// ---------------- K2: y8 = permuted fp8(8*y)  (A=xb8, Bt=Mt8) ----------------
__global__ __launch_bounds__(512)
__attribute__((amdgpu_waves_per_eu(2, 2)))
void k_proj_y(const unsigned char* __restrict__ xb8,
              const unsigned char* __restrict__ Mt8,
              unsigned char* __restrict__ y8) {
    __shared__ unsigned char lds[131072];   // 128 KiB -> 1 block/CU regardless
    const int f = blockIdx.x;
    const int m_hi = f & 7, j = f >> 3;
    const int n_t = j & 3, m_lo = j >> 2;
    const int m0 = (m_hi * 8 + m_lo) * 256, n0 = n_t * 256;

    f32x4 acc[8][4] = {};
    gemm256_fp8(xb8, Mt8, DIM, DIM, m0, n0, lds, acc);

    const int tid = threadIdx.x, w = tid >> 6, lane = tid & 63;
    const int wr = w >> 2, wc = w & 3, fr = lane & 15, fg = lane >> 4;
#pragma unroll
    for (int nf = 0; nf < 4; ++nf) {
        int n = n0 + wc * 64 + nf * 16 + fr;
        int pn = perm128(n);
#pragma unroll
        for (int mf = 0; mf < 8; ++mf) {
            int r0 = m0 + wr * 128 + mf * 16 + fg * 4;
            int pk01 = __builtin_amdgcn_cvt_pk_fp8_f32(acc[mf][nf][0] * 0.125f, acc[mf][nf][1] * 0.125f, 0, false);
            int pk23 = __builtin_amdgcn_cvt_pk_fp8_f32(acc[mf][nf][2] * 0.125f, acc[mf][nf][3] * 0.125f, 0, false);
            y8[(size_t)(r0 + 0) * DIM + pn] = (unsigned char)(pk01 & 0xff);
            y8[(size_t)(r0 + 1) * DIM + pn] = (unsigned char)((pk01 >> 8) & 0xff);
            y8[(size_t)(r0 + 2) * DIM + pn] = (unsigned char)(pk23 & 0xff);
            y8[(size_t)(r0 + 3) * DIM + pn] = (unsigned char)((pk23 >> 8) & 0xff);
        }
    }
}

// ---------------- K3: PT[t][s] = fp8(exp(acc*scl/8 + c[t])), ell[s] = rowsum ----------------
__global__ __launch_bounds__(512)
__attribute__((amdgpu_waves_per_eu(2, 2)))
void k_scores(const unsigned char* __restrict__ y8,
              const unsigned char* __restrict__ xb8,
              const float* __restrict__ c,
              unsigned char* __restrict__ PT,
              float* __restrict__ ell) {
    __shared__ unsigned char lds[131072];
    const int f = blockIdx.x;
    const int b = f & 7, j = f >> 3;
    const int mt = j & 7, nt = j >> 3;
    const unsigned char* q = y8 + (size_t)b * SEQ * DIM;
    const unsigned char* k = xb8 + (size_t)b * SEQ * DIM;
    const int m0 = mt * 256, n0 = nt * 256;

    f32x4 acc[8][4] = {};
    gemm256_fp8(q, k, DIM, DIM, m0, n0, lds, acc);

    const float scl8 = 0.00390625f;  // (1/32)/8 : y8 carries 8x
    const int tid = threadIdx.x, w = tid >> 6, lane = tid & 63;
    const int wr = w >> 2, wc = w & 3, fr = lane & 15, fg = lane >> 4;
    unsigned char* Pb = PT + (size_t)b * SEQ * SEQ;
    float cv[4];
#pragma unroll
    for (int nf = 0; nf < 4; ++nf)
        cv[nf] = c[(size_t)b * SEQ + n0 + wc * 64 + nf * 16 + fr];
#pragma unroll
    for (int mf = 0; mf < 8; ++mf) {
        const int sbase = m0 + wr * 128 + mf * 16 + fg * 4;
        float rs[4] = {0.f, 0.f, 0.f, 0.f};
#pragma unroll
        for (int nf = 0; nf < 4; ++nf) {
            int t = n0 + wc * 64 + nf * 16 + fr;
            float p0 = __expf(fmaf(acc[mf][nf][0], scl8, cv[nf]));
            float p1 = __expf(fmaf(acc[mf][nf][1], scl8, cv[nf]));
            float p2 = __expf(fmaf(acc[mf][nf][2], scl8, cv[nf]));
            float p3 = __expf(fmaf(acc[mf][nf][3], scl8, cv[nf]));
            int pk = __builtin_amdgcn_cvt_pk_fp8_f32(p0, p1, 0, false);
            pk = __builtin_amdgcn_cvt_pk_fp8_f32(p2, p3, pk, true);
            *reinterpret_cast<unsigned int*>(Pb + (size_t)t * SEQ + sbase) = (unsigned int)pk;
            f32x2 d01 = __builtin_amdgcn_cvt_pk_f32_fp8(pk, false);
            f32x2 d23 = __builtin_amdgcn_cvt_pk_f32_fp8(pk, true);
            rs[0] += d01[0]; rs[1] += d01[1]; rs[2] += d23[0]; rs[3] += d23[1];
        }
#pragma unroll
        for (int j2 = 0; j2 < 4; ++j2) {
            float r = rs[j2];
            r += __shfl_xor(r, 1);
            r += __shfl_xor(r, 2);
            r += __shfl_xor(r, 4);
            r += __shfl_xor(r, 8);
            if (fr == 0) atomicAdd(&ell[b * SEQ + sbase + j2], r);
        }
    }
}

// ---------------- K4: w[t] = sum_s PT[t][s] / ell[s] ----------------
__global__ __launch_bounds__(256) void k_colsum(const unsigned char* __restrict__ PT,
                                                const float* __restrict__ ell,
                                                float* __restrict__ w) {
    __shared__ float rel[512];
    const int b = blockIdx.z;
    const int s0 = blockIdx.x * 512;
    const int t = blockIdx.y * 256 + threadIdx.x;
    {
        int i = threadIdx.x;
        rel[i]       = 1.0f / ell[b * SEQ + s0 + i];
        rel[i + 256] = 1.0f / ell[b * SEQ + s0 + 256 + i];
    }
    __syncthreads();
    const unsigned char* Pt = PT + (size_t)b * SEQ * SEQ + (size_t)t * SEQ + s0;
    float a = 0.f;
    for (int i = 0; i < 512; i += 8) {
        uint2 pv = *reinterpret_cast<const uint2*>(Pt + i);
        f32x2 d0 = __builtin_amdgcn_cvt_pk_f32_fp8((int)pv.x, false);
        f32x2 d1 = __builtin_amdgcn_cvt_pk_f32_fp8((int)pv.x, true);
        f32x2 d2 = __builtin_amdgcn_cvt_pk_f32_fp8((int)pv.y, false);
        f32x2 d3 = __builtin_amdgcn_cvt_pk_f32_fp8((int)pv.y, true);
        a += d0[0] * rel[i]     + d0[1] * rel[i + 1] + d1[0] * rel[i + 2] + d1[1] * rel[i + 3];
        a += d2[0] * rel[i + 4] + d2[1] * rel[i + 5] + d3[0] * rel[i + 6] + d3[1] * rel[i + 7];
    }
    atomicAdd(&w[b * SEQ + t], a);
}

// ---------------- K5: g[b,d] = (1/S) sum_t w[b,t] * xb[b,t,d]  (bf16 x) ----------------
__global__ __launch_bounds__(256) void k_accx(const float* __restrict__ w,
                                              const unsigned short* __restrict__ xb,
                                              float* __restrict__ g) {
    const int b = blockIdx.y;
    const int t0 = blockIdx.x * 64 + (threadIdx.x >> 7) * 32;
    const int d8 = (threadIdx.x & 127) * 8;
    const unsigned short* xbb = xb + (size_t)b * SEQ * DIM;
    const float* wb = w + b * SEQ;
    float a[8] = {};
    for (int i = 0; i < 32; ++i) {
        int t = t0 + i;
        float wt = wb[t];
        u16x8 v = *reinterpret_cast<const u16x8*>(xbb + (size_t)t * DIM + d8);
#pragma unroll
        for (int j = 0; j < 8; ++j) a[j] += wt * bf2f(v[j]);
    }
#pragma unroll
    for (int j = 0; j < 8; ++j)
        atomicAdd(&g[b * DIM + d8 + j], a[j] * (1.0f / (float)SEQ));
}

// ---------------- K6: out[b,n] += sum_{d in chunk} g[b,d] * Wv[d,n] ----------------
__global__ __launch_bounds__(256) void k_out2(const float* __restrict__ g,
                                              const float* __restrict__ Wv,
                                              float* __restrict__ out) {
    int b = blockIdx.y;
    int n = blockIdx.x * 256 + threadIdx.x;
    int d0 = blockIdx.z * 64;
    const float* gb = g + b * DIM;
    float acc = 0.f;
#pragma unroll
    for (int d = 0; d < 64; ++d)
        acc += gb[d0 + d] * Wv[(size_t)(d0 + d) * DIM + n];
    atomicAdd(&out[b * DIM + n], acc);
}

extern "C" void kernel_launch(void* const* d_in, const int* in_sizes, int n_in,
                              void* d_out, int out_size, void* d_ws, size_t ws_size,
                              hipStream_t stream) {
    const float* x  = (const float*)d_in[0];
    const float* Wq = (const float*)d_in[1];
    const float* bq = (const float*)d_in[2];
    const float* Wk = (const float*)d_in[3];
    const float* bk = (const float*)d_in[4];   // unused (softmax-invariant)
    const float* Wv = (const float*)d_in[5];
    const float* bv = (const float*)d_in[6];
    float* out = (float*)d_out;
    (void)bk;

    char* ws = (char*)d_ws;
    unsigned short* xb  = (unsigned short*)(ws);                    //  33,554,432
    unsigned short* wkb = (unsigned short*)(ws + 33554432ull);      //   2,097,152
    unsigned short* wqb = (unsigned short*)(ws + 35651584ull);      //   2,097,152
    unsigned char*  Mt8 = (unsigned char*)(ws + 37748736ull);       //   1,048,576
    unsigned char*  xb8 = (unsigned char*)(ws + 38797312ull);       //  16,777,216
    unsigned char*  y8  = (unsigned char*)(ws + 55574528ull);       //  16,777,216
    unsigned char*  PT  = (unsigned char*)(ws + 72351744ull);       //  33,554,432
    float*          ell = (float*)(ws + 105906176ull);              //      65,536
    float*          w   = (float*)(ws + 105971712ull);              //      65,536
    float*          g   = (float*)(ws + 106037248ull);              //      32,768
    float*          c   = (float*)(ws + 106070016ull);              //      65,536
    float*          u   = (float*)(ws + 106135552ull);              //       4,096

    // single memset: ell + w + g contiguous (163,840 bytes)
    hipMemsetAsync(ell, 0, 163840, stream);

    k_prep<<<dim3(2336), 256, 0, stream>>>(Wk, Wq, bq, bv, wkb, wqb, u, out);
    k_cvtx_mm<<<dim3(64 + MTOT), 256, 0, stream>>>(x, u, wkb, wqb, xb, xb8, c, Mt8);
    k_proj_y<<<dim3(256), 512, 0, stream>>>(xb8, Mt8, y8);
    k_scores<<<dim3(512), 512, 0, stream>>>(y8, xb8, c, PT, ell);
    k_colsum<<<dim3(SEQ / 512, SEQ / 256, NB), 256, 0, stream>>>(PT, ell, w);
    k_accx<<<dim3(SEQ / 64, NB), 256, 0, stream>>>(w, xb, g);
    k_out2<<<dim3(DIM / 256, NB, 16), 256, 0, stream>>>(g, Wv, out);
}

// Round 18
// 183.457 us; speedup vs baseline: 1.0301x; 1.0288x over previous
//
#include <hip/hip_runtime.h>

// ---------------------------------------------------------------------------
// AttentionFuse: out[b,d] = mean_s( softmax((x Wq + bq)(x Wk + bk)^T / 32) @ (x Wv + bv) )
// Algebra:
//   mean_s(attn @ V) = sum_t a[t] V[t,:]  =>  out = (a^T x) Wv + bv   (V GEMM gone)
//   S = x (Wq Wk^T) x^T  =>  y = x Mt^T, Mt = Wk Wq^T (2.1 GF)  =>  S = y x^T
//   bias: P[s,t] = exp(scale*S + c[t]),  c[t] = scale * x[t].u,  u = Wk bq
// R18: exact revert to R13 (best verified: 183.8us, absmax 2.44e-4).
//   R17's fp8-x in k_accx broke the error budget (1.34e-3 > 1.26e-3):
//   correct propagation gives ~5e-4 added error, not 5e-5 — bf16 x for
//   the final weighted-average is part of the accuracy budget.
// ---------------------------------------------------------------------------

using bf16x8 = __attribute__((ext_vector_type(8))) __bf16;
using u16x8  = __attribute__((ext_vector_type(8))) unsigned short;
using f32x4  = __attribute__((ext_vector_type(4))) float;
using f32x2  = __attribute__((ext_vector_type(2))) float;
using i64x2  = __attribute__((ext_vector_type(2))) long;

#define NB 8
#define SEQ 2048
#define DIM 1024
#define MTOT (NB * SEQ)          // 16384

__device__ __forceinline__ unsigned short f2bf(float f) {
    unsigned int u = __float_as_uint(f);
    u = u + 0x7FFFu + ((u >> 16) & 1u);   // RNE
    return (unsigned short)(u >> 16);
}
__device__ __forceinline__ float bf2f(unsigned short h) {
    return __uint_as_float(((unsigned int)h) << 16);
}
// byte position of element k within a permuted 128-elem fp8 K-block
__device__ __forceinline__ int perm128(int n) {
    return (n & ~127) + ((n >> 3) & 3) * 32 + ((n & 127) >> 5) * 8 + (n & 7);
}

__device__ __forceinline__ void async16(const unsigned short* g, unsigned short* l) {
    __builtin_amdgcn_global_load_lds(
        (const __attribute__((address_space(1))) void*)g,
        (__attribute__((address_space(3))) void*)l, 16, 0, 0);
}
__device__ __forceinline__ void async16b(const unsigned char* g, unsigned char* l) {
    __builtin_amdgcn_global_load_lds(
        (const __attribute__((address_space(1))) void*)g,
        (__attribute__((address_space(3))) void*)l, 16, 0, 0);
}
__device__ __forceinline__ f32x4 mfma8(long a, long b, f32x4 c) {
    return __builtin_amdgcn_mfma_f32_16x16x32_fp8_fp8(a, b, c, 0, 0, 0);
}
// forced 16B LDS read (one ds_read_b128; LLVM would split an i64x2 load)
__device__ __forceinline__ i64x2 ds_read128(const unsigned char* base, int off) {
    unsigned addr = (unsigned)(size_t)(
        (const __attribute__((address_space(3))) unsigned char*)base + off);
    i64x2 r;
    asm volatile("ds_read_b128 %0, %1" : "=v"(r) : "v"(addr));
    return r;
}

// ---------------- K0 (merged prep): cvt_w x2, u = Wk bq, out = bv ----------------
__global__ __launch_bounds__(256) void k_prep(const float* __restrict__ Wk,
                                              const float* __restrict__ Wq,
                                              const float* __restrict__ bq,
                                              const float* __restrict__ bv,
                                              unsigned short* __restrict__ wkb,
                                              unsigned short* __restrict__ wqb,
                                              float* __restrict__ u,
                                              float* __restrict__ out) {
    const int bid = blockIdx.x;
    if (bid < 2048) {                       // Wk,Wq fp32 -> bf16
        const float* src = (bid >= 1024) ? Wq : Wk;
        unsigned short* dst = (bid >= 1024) ? wqb : wkb;
        size_t i = ((size_t)(bid & 1023) * 256 + threadIdx.x) * 4;
        float4 v = *reinterpret_cast<const float4*>(src + i);
        ushort4 o;
        o.x = f2bf(v.x); o.y = f2bf(v.y); o.z = f2bf(v.z); o.w = f2bf(v.w);
        *reinterpret_cast<ushort4*>(dst + i) = o;
    } else if (bid < 2304) {                // u[row] = Wk[row,:].bq
        const int wave = threadIdx.x >> 6, lane = threadIdx.x & 63;
        const int row = (bid - 2048) * 4 + wave;
        const float* wr = Wk + (size_t)row * DIM;
        float s = 0.f;
#pragma unroll
        for (int p = 0; p < 4; ++p) {
            int col = p * 256 + lane * 4;
            float4 v = *reinterpret_cast<const float4*>(wr + col);
            float4 b = *reinterpret_cast<const float4*>(bq + col);
            s += v.x * b.x + v.y * b.y + v.z * b.z + v.w * b.w;
        }
#pragma unroll
        for (int off = 32; off; off >>= 1) s += __shfl_xor(s, off);
        if (lane == 0) u[row] = s;
    } else {                                // out[b,n] = bv[n]
        int i = (bid - 2304) * 256 + threadIdx.x;
        out[i] = bv[i & (DIM - 1)];
    }
}

// ---------------- 128x128 tile bf16 GEMM (for Mt = Wk Wq^T) ----------------
__device__ __forceinline__ void gemm_bt_tile128(const unsigned short* __restrict__ A,
                                                const unsigned short* __restrict__ Bt,
                                                int K, int m0, int n0, int lda, int ldb,
                                                unsigned short* ldsA, unsigned short* ldsB,
                                                f32x4 acc[4][4]) {
    const int tid  = threadIdx.x;
    const int wave = tid >> 6;
    const int lane = tid & 63;
    const int lrow = lane >> 3;
    const int lcol = lane & 7;
    const int wm = (wave >> 1) * 64;
    const int wn = (wave & 1) * 64;
    const int fr = lane & 15;
    const int fg = lane >> 4;

    for (int k0 = 0; k0 < K; k0 += 64) {
#pragma unroll
        for (int r = 0; r < 4; ++r) {
            int row = r * 32 + wave * 8 + lrow;
            async16(A + (size_t)(m0 + row) * lda + k0 + lcol * 8, ldsA + r * 2048 + wave * 512);
            async16(Bt + (size_t)(n0 + row) * ldb + k0 + lcol * 8, ldsB + r * 2048 + wave * 512);
        }
        __syncthreads();
#pragma unroll
        for (int ks = 0; ks < 2; ++ks) {
            bf16x8 af[4], bfr[4];
#pragma unroll
            for (int mf = 0; mf < 4; ++mf)
                af[mf] = *reinterpret_cast<const bf16x8*>(ldsA + (wm + mf * 16 + fr) * 64 + ks * 32 + fg * 8);
#pragma unroll
            for (int nf = 0; nf < 4; ++nf)
                bfr[nf] = *reinterpret_cast<const bf16x8*>(ldsB + (wn + nf * 16 + fr) * 64 + ks * 32 + fg * 8);
#pragma unroll
            for (int mf = 0; mf < 4; ++mf)
#pragma unroll
                for (int nf = 0; nf < 4; ++nf)
                    acc[mf][nf] = __builtin_amdgcn_mfma_f32_16x16x32_bf16(af[mf], bfr[nf], acc[mf][nf], 0, 0, 0);
        }
        __syncthreads();
    }
}

// ---------------- K1 (fused): blocks 0-63: Mt8 = perm-fp8(64*Wk Wq^T);
//                  blocks 64+: x -> bf16 + perm-fp8, c[row] = scale*x.u ----
__global__ __launch_bounds__(256) void k_cvtx_mm(const float* __restrict__ x,
                                                 const float* __restrict__ u,
                                                 const unsigned short* __restrict__ wkb,
                                                 const unsigned short* __restrict__ wqb,
                                                 unsigned short* __restrict__ xb,
                                                 unsigned char* __restrict__ xb8,
                                                 float* __restrict__ c,
                                                 unsigned char* __restrict__ Mt8) {
    __shared__ unsigned short ldsA[8192];
    __shared__ unsigned short ldsB[8192];
    const int bid = blockIdx.x;
    if (bid < 64) {
        int m0 = (bid & 7) * 128, n0 = (bid >> 3) * 128;
        f32x4 acc[4][4] = {};
        gemm_bt_tile128(wkb, wqb, DIM, m0, n0, DIM, DIM, ldsA, ldsB, acc);
        const int lane = threadIdx.x & 63, wave = threadIdx.x >> 6;
        const int wm = (wave >> 1) * 64, wn = (wave & 1) * 64;
        const int fr = lane & 15, fg = lane >> 4;
#pragma unroll
        for (int nf = 0; nf < 4; ++nf) {
            int n = n0 + wn + nf * 16 + fr;
            int pn = perm128(n);
#pragma unroll
            for (int mf = 0; mf < 4; ++mf) {
                int r0 = m0 + wm + mf * 16 + fg * 4;
                int pk01 = __builtin_amdgcn_cvt_pk_fp8_f32(acc[mf][nf][0] * 64.f, acc[mf][nf][1] * 64.f, 0, false);
                int pk23 = __builtin_amdgcn_cvt_pk_fp8_f32(acc[mf][nf][2] * 64.f, acc[mf][nf][3] * 64.f, 0, false);
                Mt8[(size_t)(r0 + 0) * DIM + pn] = (unsigned char)(pk01 & 0xff);
                Mt8[(size_t)(r0 + 1) * DIM + pn] = (unsigned char)((pk01 >> 8) & 0xff);
                Mt8[(size_t)(r0 + 2) * DIM + pn] = (unsigned char)(pk23 & 0xff);
                Mt8[(size_t)(r0 + 3) * DIM + pn] = (unsigned char)((pk23 >> 8) & 0xff);
            }
        }
    } else {
        float* red = (float*)ldsA;
        const int row = bid - 64, tid = threadIdx.x;
        size_t i = (size_t)row * DIM + tid * 4;
        float4 v = *reinterpret_cast<const float4*>(x + i);
        ushort4 o;
        o.x = f2bf(v.x); o.y = f2bf(v.y); o.z = f2bf(v.z); o.w = f2bf(v.w);
        *reinterpret_cast<ushort4*>(xb + i) = o;
        int pk = __builtin_amdgcn_cvt_pk_fp8_f32(v.x, v.y, 0, false);
        pk = __builtin_amdgcn_cvt_pk_fp8_f32(v.z, v.w, pk, true);
        int pp = perm128(tid * 4);   // 4 elems stay in one 8B chunk
        *reinterpret_cast<unsigned int*>(xb8 + (size_t)row * DIM + pp) = (unsigned int)pk;
        float4 uv = *reinterpret_cast<const float4*>(u + tid * 4);
        float s = v.x * uv.x + v.y * uv.y + v.z * uv.z + v.w * uv.w;
#pragma unroll
        for (int off = 32; off; off >>= 1) s += __shfl_xor(s, off);
        if ((tid & 63) == 0) red[tid >> 6] = s;
        __syncthreads();
        if (tid == 0) c[row] = 0.03125f * (red[0] + red[1] + red[2] + red[3]);
    }
}

// ---------------------------------------------------------------------------
// 256x256 fp8 GEMM core. K = 1024, BK = 128 fp8 (permuted rows). Fragment
// reads = forced ds_read_b128 at 16B-slot XOR-swizzled addrs.
// 8 K-tiles, 4 iters, 1 barrier/phase, vmcnt(4) at phases 4/8.
// ---------------------------------------------------------------------------

#define STAGE8(gbase, ld, dstoff)                                         \
    do {                                                                  \
        async16b((gbase), ldsw + (dstoff));                               \
        async16b((gbase) + 8 * (size_t)(ld), ldsw + (dstoff) + 1024);     \
    } while (0)
#define STAGE8_A(buf, half, kt) STAGE8(gA + (size_t)((half) * 128) * lda + (kt) * 128, lda, (buf) * 32768 + (half) * 16384)
#define STAGE8_B(buf, half, kt) STAGE8(gB + (size_t)((half) * 128) * ldb + (kt) * 128, ldb, 65536 + (buf) * 32768 + (half) * 16384)

#define FRAG8(base_b, row, colb) \
    ds_read128(lds, (base_b) + (row) * 128 + ((colb) ^ (((row) & 7) << 4)))

#define READ8_A(dbuf, mh)                                                     \
    _Pragma("unroll") for (int m2 = 0; m2 < 4; ++m2) {                        \
        int arow = ((mh) * 4 + m2) * 16 + fr;                                 \
        _Pragma("unroll") for (int h = 0; h < 2; ++h)                         \
            afc[(mh) * 4 + m2][h] =                                           \
                FRAG8((dbuf) * 32768 + wr * 16384, arow, fg * 32 + h * 16);   \
    }
#define READ8_B(dbuf, nh)                                                     \
    _Pragma("unroll") for (int n2 = 0; n2 < 2; ++n2) {                        \
        int brow = (wc & 1) * 64 + ((nh) * 2 + n2) * 16 + fr;                 \
        _Pragma("unroll") for (int h = 0; h < 2; ++h)                         \
            bfc[nh][n2][h] =                                                  \
                FRAG8(65536 + (dbuf) * 32768 + (wc >> 1) * 16384, brow,       \
                      fg * 32 + h * 16);                                      \
    }

#define VM4 asm volatile("s_waitcnt vmcnt(4)" ::: "memory")

#define PHASE8(mh, nh, STG, VM, PF)                                           \
    do {                                                                      \
        STG;                                                                  \
        VM;                                                                   \
        asm volatile("s_barrier" ::: "memory");                               \
        asm volatile("s_waitcnt lgkmcnt(0)" ::: "memory");                    \
        __builtin_amdgcn_sched_barrier(0);                                    \
        PF;                                                                   \
        __builtin_amdgcn_sched_barrier(0);                                    \
        __builtin_amdgcn_s_setprio(1);                                        \
        _Pragma("unroll") for (int m2 = 0; m2 < 4; ++m2)                      \
        _Pragma("unroll") for (int n2 = 0; n2 < 2; ++n2) {                    \
            f32x4& a = acc[(mh) * 4 + m2][(nh) * 2 + n2];                     \
            a = mfma8(afc[(mh) * 4 + m2][0][0], bfc[nh][n2][0][0], a);        \
            a = mfma8(afc[(mh) * 4 + m2][0][1], bfc[nh][n2][0][1], a);        \
            a = mfma8(afc[(mh) * 4 + m2][1][0], bfc[nh][n2][1][0], a);        \
            a = mfma8(afc[(mh) * 4 + m2][1][1], bfc[nh][n2][1][1], a);        \
        }                                                                     \
        __builtin_amdgcn_s_setprio(0);                                        \
    } while (0)

__device__ __forceinline__ void gemm256_fp8(const unsigned char* __restrict__ A,
                                            const unsigned char* __restrict__ Bt,
                                            int lda, int ldb, int m0, int n0,
                                            unsigned char* lds, f32x4 (&acc)[8][4]) {
    constexpr int NKT = 1024 / 128;  // 8 K-tiles
    constexpr int NIT = NKT / 2;     // 4 iterations
    const int tid = threadIdx.x;
    const int w = tid >> 6, lane = tid & 63;
    const int wr = w >> 2, wc = w & 3;
    const int fr = lane & 15, fg = lane >> 4;
    const int r8 = lane >> 3, slot = (lane & 7) ^ r8;

    const unsigned char* gA = A + (size_t)(m0 + w * 16 + r8) * lda + slot * 16;
    const unsigned char* gB = Bt + (size_t)(n0 + w * 16 + r8) * ldb + slot * 16;
    unsigned char* ldsw = lds + w * 2048;

    i64x2 afc[8][2];
    i64x2 bfc[2][2][2];

    STAGE8_A(0, 0, 0); STAGE8_A(0, 1, 0); STAGE8_B(0, 0, 0); STAGE8_B(0, 1, 0);
    STAGE8_A(1, 0, 1); STAGE8_A(1, 1, 1);
    VM4;
    asm volatile("s_barrier" ::: "memory");
    READ8_A(0, 0); READ8_B(0, 0);

    for (int it = 0; it < NIT; ++it) {
        const int t1 = 2 * it + 1;
        const int ka = (2 * it + 2) & (NKT - 1);
        const int kb = (2 * it + 3) & (NKT - 1);
        PHASE8(0, 0, STAGE8_B(1, 0, t1), , READ8_A(0, 1));
        PHASE8(1, 0, STAGE8_B(1, 1, t1), , READ8_B(0, 1));
        PHASE8(0, 1, STAGE8_A(0, 0, ka), , );
        PHASE8(1, 1, STAGE8_A(0, 1, ka), VM4, READ8_A(1, 0); READ8_B(1, 0));
        PHASE8(0, 0, STAGE8_B(0, 0, ka), , READ8_A(1, 1));
        PHASE8(1, 0, STAGE8_B(0, 1, ka), , READ8_B(1, 1));
        PHASE8(0, 1, STAGE8_A(1, 0, kb), , );
        PHASE8(1, 1, STAGE8_A(1, 1, kb), VM4, READ8_A(0, 0); READ8_B(0, 0));
    }
    asm volatile("s_waitcnt vmcnt(0) lgkmcnt(0)" ::: "memory");
}

// ---------------- K2: y8 = permuted fp8(8*y)  (A=xb8, Bt=Mt8) ----------------
__global__ __launch_bounds__(512, 1) void k_proj_y(const unsigned char* __restrict__ xb8,
                                                   const unsigned char* __restrict__ Mt8,
                                                   unsigned char* __restrict__ y8) {
    __shared__ unsigned char lds[131072];   // 128 KiB
    const int f = blockIdx.x;
    const int m_hi = f & 7, j = f >> 3;
    const int n_t = j & 3, m_lo = j >> 2;
    const int m0 = (m_hi * 8 + m_lo) * 256, n0 = n_t * 256;

    f32x4 acc[8][4] = {};
    gemm256_fp8(xb8, Mt8, DIM, DIM, m0, n0, lds, acc);

    const int tid = threadIdx.x, w = tid >> 6, lane = tid & 63;
    const int wr = w >> 2, wc = w & 3, fr = lane & 15, fg = lane >> 4;
#pragma unroll
    for (int nf = 0; nf < 4; ++nf) {
        int n = n0 + wc * 64 + nf * 16 + fr;
        int pn = perm128(n);
#pragma unroll
        for (int mf = 0; mf < 8; ++mf) {
            int r0 = m0 + wr * 128 + mf * 16 + fg * 4;
            int pk01 = __builtin_amdgcn_cvt_pk_fp8_f32(acc[mf][nf][0] * 0.125f, acc[mf][nf][1] * 0.125f, 0, false);
            int pk23 = __builtin_amdgcn_cvt_pk_fp8_f32(acc[mf][nf][2] * 0.125f, acc[mf][nf][3] * 0.125f, 0, false);
            y8[(size_t)(r0 + 0) * DIM + pn] = (unsigned char)(pk01 & 0xff);
            y8[(size_t)(r0 + 1) * DIM + pn] = (unsigned char)((pk01 >> 8) & 0xff);
            y8[(size_t)(r0 + 2) * DIM + pn] = (unsigned char)(pk23 & 0xff);
            y8[(size_t)(r0 + 3) * DIM + pn] = (unsigned char)((pk23 >> 8) & 0xff);
        }
    }
}

// ---------------- K3: PT[t][s] = fp8(exp(acc*scl/8 + c[t])), ell[s] = rowsum ----------------
__global__ __launch_bounds__(512, 1) void k_scores(const unsigned char* __restrict__ y8,
                                                   const unsigned char* __restrict__ xb8,
                                                   const float* __restrict__ c,
                                                   unsigned char* __restrict__ PT,
                                                   float* __restrict__ ell) {
    __shared__ unsigned char lds[131072];
    const int f = blockIdx.x;
    const int b = f & 7, j = f >> 3;
    const int mt = j & 7, nt = j >> 3;
    const unsigned char* q = y8 + (size_t)b * SEQ * DIM;
    const unsigned char* k = xb8 + (size_t)b * SEQ * DIM;
    const int m0 = mt * 256, n0 = nt * 256;

    f32x4 acc[8][4] = {};
    gemm256_fp8(q, k, DIM, DIM, m0, n0, lds, acc);

    const float scl8 = 0.00390625f;  // (1/32)/8 : y8 carries 8x
    const int tid = threadIdx.x, w = tid >> 6, lane = tid & 63;
    const int wr = w >> 2, wc = w & 3, fr = lane & 15, fg = lane >> 4;
    unsigned char* Pb = PT + (size_t)b * SEQ * SEQ;
    float cv[4];
#pragma unroll
    for (int nf = 0; nf < 4; ++nf)
        cv[nf] = c[(size_t)b * SEQ + n0 + wc * 64 + nf * 16 + fr];
#pragma unroll
    for (int mf = 0; mf < 8; ++mf) {
        const int sbase = m0 + wr * 128 + mf * 16 + fg * 4;
        float rs[4] = {0.f, 0.f, 0.f, 0.f};
#pragma unroll
        for (int nf = 0; nf < 4; ++nf) {
            int t = n0 + wc * 64 + nf * 16 + fr;
            float p0 = __expf(fmaf(acc[mf][nf][0], scl8, cv[nf]));
            float p1 = __expf(fmaf(acc[mf][nf][1], scl8, cv[nf]));
            float p2 = __expf(fmaf(acc[mf][nf][2], scl8, cv[nf]));
            float p3 = __expf(fmaf(acc[mf][nf][3], scl8, cv[nf]));
            int pk = __builtin_amdgcn_cvt_pk_fp8_f32(p0, p1, 0, false);
            pk = __builtin_amdgcn_cvt_pk_fp8_f32(p2, p3, pk, true);
            *reinterpret_cast<unsigned int*>(Pb + (size_t)t * SEQ + sbase) = (unsigned int)pk;
            f32x2 d01 = __builtin_amdgcn_cvt_pk_f32_fp8(pk, false);
            f32x2 d23 = __builtin_amdgcn_cvt_pk_f32_fp8(pk, true);
            rs[0] += d01[0]; rs[1] += d01[1]; rs[2] += d23[0]; rs[3] += d23[1];
        }
#pragma unroll
        for (int j2 = 0; j2 < 4; ++j2) {
            float r = rs[j2];
            r += __shfl_xor(r, 1);
            r += __shfl_xor(r, 2);
            r += __shfl_xor(r, 4);
            r += __shfl_xor(r, 8);
            if (fr == 0) atomicAdd(&ell[b * SEQ + sbase + j2], r);
        }
    }
}

// ---------------- K4: w[t] = sum_s PT[t][s] / ell[s] ----------------
__global__ __launch_bounds__(256) void k_colsum(const unsigned char* __restrict__ PT,
                                                const float* __restrict__ ell,
                                                float* __restrict__ w) {
    __shared__ float rel[512];
    const int b = blockIdx.z;
    const int s0 = blockIdx.x * 512;
    const int t = blockIdx.y * 256 + threadIdx.x;
    {
        int i = threadIdx.x;
        rel[i]       = 1.0f / ell[b * SEQ + s0 + i];
        rel[i + 256] = 1.0f / ell[b * SEQ + s0 + 256 + i];
    }
    __syncthreads();
    const unsigned char* Pt = PT + (size_t)b * SEQ * SEQ + (size_t)t * SEQ + s0;
    float a = 0.f;
    for (int i = 0; i < 512; i += 8) {
        uint2 pv = *reinterpret_cast<const uint2*>(Pt + i);
        f32x2 d0 = __builtin_amdgcn_cvt_pk_f32_fp8((int)pv.x, false);
        f32x2 d1 = __builtin_amdgcn_cvt_pk_f32_fp8((int)pv.x, true);
        f32x2 d2 = __builtin_amdgcn_cvt_pk_f32_fp8((int)pv.y, false);
        f32x2 d3 = __builtin_amdgcn_cvt_pk_f32_fp8((int)pv.y, true);
        a += d0[0] * rel[i]     + d0[1] * rel[i + 1] + d1[0] * rel[i + 2] + d1[1] * rel[i + 3];
        a += d2[0] * rel[i + 4] + d2[1] * rel[i + 5] + d3[0] * rel[i + 6] + d3[1] * rel[i + 7];
    }
    atomicAdd(&w[b * SEQ + t], a);
}

// ---------------- K5: g[b,d] = (1/S) sum_t w[b,t] * xb[b,t,d]  (bf16 x) ----------------
__global__ __launch_bounds__(256) void k_accx(const float* __restrict__ w,
                                              const unsigned short* __restrict__ xb,
                                              float* __restrict__ g) {
    const int b = blockIdx.y;
    const int t0 = blockIdx.x * 64 + (threadIdx.x >> 7) * 32;
    const int d8 = (threadIdx.x & 127) * 8;
    const unsigned short* xbb = xb + (size_t)b * SEQ * DIM;
    const float* wb = w + b * SEQ;
    float a[8] = {};
    for (int i = 0; i < 32; ++i) {
        int t = t0 + i;
        float wt = wb[t];
        u16x8 v = *reinterpret_cast<const u16x8*>(xbb + (size_t)t * DIM + d8);
#pragma unroll
        for (int j = 0; j < 8; ++j) a[j] += wt * bf2f(v[j]);
    }
#pragma unroll
    for (int j = 0; j < 8; ++j)
        atomicAdd(&g[b * DIM + d8 + j], a[j] * (1.0f / (float)SEQ));
}

// ---------------- K6: out[b,n] += sum_{d in chunk} g[b,d] * Wv[d,n] ----------------
__global__ __launch_bounds__(256) void k_out2(const float* __restrict__ g,
                                              const float* __restrict__ Wv,
                                              float* __restrict__ out) {
    int b = blockIdx.y;
    int n = blockIdx.x * 256 + threadIdx.x;
    int d0 = blockIdx.z * 64;
    const float* gb = g + b * DIM;
    float acc = 0.f;
#pragma unroll
    for (int d = 0; d < 64; ++d)
        acc += gb[d0 + d] * Wv[(size_t)(d0 + d) * DIM + n];
    atomicAdd(&out[b * DIM + n], acc);
}

extern "C" void kernel_launch(void* const* d_in, const int* in_sizes, int n_in,
                              void* d_out, int out_size, void* d_ws, size_t ws_size,
                              hipStream_t stream) {
    const float* x  = (const float*)d_in[0];
    const float* Wq = (const float*)d_in[1];
    const float* bq = (const float*)d_in[2];
    const float* Wk = (const float*)d_in[3];
    const float* bk = (const float*)d_in[4];   // unused (softmax-invariant)
    const float* Wv = (const float*)d_in[5];
    const float* bv = (const float*)d_in[6];
    float* out = (float*)d_out;
    (void)bk;

    char* ws = (char*)d_ws;
    unsigned short* xb  = (unsigned short*)(ws);                    //  33,554,432
    unsigned short* wkb = (unsigned short*)(ws + 33554432ull);      //   2,097,152
    unsigned short* wqb = (unsigned short*)(ws + 35651584ull);      //   2,097,152
    unsigned char*  Mt8 = (unsigned char*)(ws + 37748736ull);       //   1,048,576
    unsigned char*  xb8 = (unsigned char*)(ws + 38797312ull);       //  16,777,216
    unsigned char*  y8  = (unsigned char*)(ws + 55574528ull);       //  16,777,216
    unsigned char*  PT  = (unsigned char*)(ws + 72351744ull);       //  33,554,432
    float*          ell = (float*)(ws + 105906176ull);              //      65,536
    float*          w   = (float*)(ws + 105971712ull);              //      65,536
    float*          g   = (float*)(ws + 106037248ull);              //      32,768
    float*          c   = (float*)(ws + 106070016ull);              //      65,536
    float*          u   = (float*)(ws + 106135552ull);              //       4,096

    // single memset: ell + w + g contiguous (163,840 bytes)
    hipMemsetAsync(ell, 0, 163840, stream);

    k_prep<<<dim3(2336), 256, 0, stream>>>(Wk, Wq, bq, bv, wkb, wqb, u, out);
    k_cvtx_mm<<<dim3(64 + MTOT), 256, 0, stream>>>(x, u, wkb, wqb, xb, xb8, c, Mt8);
    k_proj_y<<<dim3(256), 512, 0, stream>>>(xb8, Mt8, y8);
    k_scores<<<dim3(512), 512, 0, stream>>>(y8, xb8, c, PT, ell);
    k_colsum<<<dim3(SEQ / 512, SEQ / 256, NB), 256, 0, stream>>>(PT, ell, w);
    k_accx<<<dim3(SEQ / 64, NB), 256, 0, stream>>>(w, xb, g);
    k_out2<<<dim3(DIM / 256, NB, 16), 256, 0, stream>>>(g, Wv, out);
}

// Round 19
// 178.075 us; speedup vs baseline: 1.0612x; 1.0302x over previous
//
#include <hip/hip_runtime.h>

// ---------------------------------------------------------------------------
// AttentionFuse: out[b,d] = mean_s( softmax((x Wq + bq)(x Wk + bk)^T / 32) @ (x Wv + bv) )
// Algebra:
//   mean_s(attn @ V) = sum_t a[t] V[t,:]  =>  out = (a^T x) Wv + bv   (V GEMM gone)
//   S = x (Wq Wk^T) x^T  =>  y = x Mt^T, Mt = Wk Wq^T (2.1 GF)  =>  S = y x^T
//   bias: P[s,t] = exp(scale*S + c[t]),  c[t] = scale * x[t].u,  u = Wk bq
// R19: fp8 intra-row permutation changed so fragment reads hit column-bytes
//   h*64 + fg*16 — byte-identical bank pattern to the measured-zero bf16
//   core (slot = (4h+fg) ^ (row&7)). Old fg*32+h*16 pattern collapsed the
//   wave onto 8 bank-starts (8 lanes each) -> the residual 3.34M conflicts.
//   perm128: k(sub,fg,b) -> (sub>>1)*64 + fg*16 + (sub&1)*8 + b (bijective).
//   Also: memset folded into k_prep (one fewer graph node).
// ---------------------------------------------------------------------------

using bf16x8 = __attribute__((ext_vector_type(8))) __bf16;
using u16x8  = __attribute__((ext_vector_type(8))) unsigned short;
using f32x4  = __attribute__((ext_vector_type(4))) float;
using f32x2  = __attribute__((ext_vector_type(2))) float;
using i64x2  = __attribute__((ext_vector_type(2))) long;

#define NB 8
#define SEQ 2048
#define DIM 1024
#define MTOT (NB * SEQ)          // 16384

__device__ __forceinline__ unsigned short f2bf(float f) {
    unsigned int u = __float_as_uint(f);
    u = u + 0x7FFFu + ((u >> 16) & 1u);   // RNE
    return (unsigned short)(u >> 16);
}
__device__ __forceinline__ float bf2f(unsigned short h) {
    return __uint_as_float(((unsigned int)h) << 16);
}
// byte position of element k within a permuted 128-elem fp8 K-block:
// k = sub*32 + fg*8 + b  ->  (sub>>1)*64 + fg*16 + (sub&1)*8 + b
__device__ __forceinline__ int perm128(int n) {
    return (n & ~127) + ((n >> 6) & 1) * 64 + ((n >> 3) & 3) * 16
         + ((n >> 5) & 1) * 8 + (n & 7);
}

__device__ __forceinline__ void async16(const unsigned short* g, unsigned short* l) {
    __builtin_amdgcn_global_load_lds(
        (const __attribute__((address_space(1))) void*)g,
        (__attribute__((address_space(3))) void*)l, 16, 0, 0);
}
__device__ __forceinline__ void async16b(const unsigned char* g, unsigned char* l) {
    __builtin_amdgcn_global_load_lds(
        (const __attribute__((address_space(1))) void*)g,
        (__attribute__((address_space(3))) void*)l, 16, 0, 0);
}
__device__ __forceinline__ f32x4 mfma8(long a, long b, f32x4 c) {
    return __builtin_amdgcn_mfma_f32_16x16x32_fp8_fp8(a, b, c, 0, 0, 0);
}
// forced 16B LDS read (one ds_read_b128)
__device__ __forceinline__ i64x2 ds_read128(const unsigned char* base, int off) {
    unsigned addr = (unsigned)(size_t)(
        (const __attribute__((address_space(3))) unsigned char*)base + off);
    i64x2 r;
    asm volatile("ds_read_b128 %0, %1" : "=v"(r) : "v"(addr));
    return r;
}

// ---------------- K0 (merged prep): cvt_w x2, u = Wk bq, out = bv, zero ell/w/g ----
__global__ __launch_bounds__(256) void k_prep(const float* __restrict__ Wk,
                                              const float* __restrict__ Wq,
                                              const float* __restrict__ bq,
                                              const float* __restrict__ bv,
                                              unsigned short* __restrict__ wkb,
                                              unsigned short* __restrict__ wqb,
                                              float* __restrict__ u,
                                              float* __restrict__ out,
                                              float* __restrict__ zbase) {
    const int bid = blockIdx.x;
    if (bid < 2048) {                       // Wk,Wq fp32 -> bf16
        const float* src = (bid >= 1024) ? Wq : Wk;
        unsigned short* dst = (bid >= 1024) ? wqb : wkb;
        size_t i = ((size_t)(bid & 1023) * 256 + threadIdx.x) * 4;
        float4 v = *reinterpret_cast<const float4*>(src + i);
        ushort4 o;
        o.x = f2bf(v.x); o.y = f2bf(v.y); o.z = f2bf(v.z); o.w = f2bf(v.w);
        *reinterpret_cast<ushort4*>(dst + i) = o;
    } else if (bid < 2304) {                // u[row] = Wk[row,:].bq
        const int wave = threadIdx.x >> 6, lane = threadIdx.x & 63;
        const int row = (bid - 2048) * 4 + wave;
        const float* wr = Wk + (size_t)row * DIM;
        float s = 0.f;
#pragma unroll
        for (int p = 0; p < 4; ++p) {
            int col = p * 256 + lane * 4;
            float4 v = *reinterpret_cast<const float4*>(wr + col);
            float4 b = *reinterpret_cast<const float4*>(bq + col);
            s += v.x * b.x + v.y * b.y + v.z * b.z + v.w * b.w;
        }
#pragma unroll
        for (int off = 32; off; off >>= 1) s += __shfl_xor(s, off);
        if (lane == 0) u[row] = s;
    } else if (bid < 2336) {                // out[b,n] = bv[n]
        int i = (bid - 2304) * 256 + threadIdx.x;
        out[i] = bv[i & (DIM - 1)];
    } else {                                // zero ell+w+g (40960 floats)
        int i = (bid - 2336) * 256 + threadIdx.x;
        zbase[i] = 0.f;
    }
}

// ---------------- 128x128 tile bf16 GEMM (for Mt = Wk Wq^T) ----------------
__device__ __forceinline__ void gemm_bt_tile128(const unsigned short* __restrict__ A,
                                                const unsigned short* __restrict__ Bt,
                                                int K, int m0, int n0, int lda, int ldb,
                                                unsigned short* ldsA, unsigned short* ldsB,
                                                f32x4 acc[4][4]) {
    const int tid  = threadIdx.x;
    const int wave = tid >> 6;
    const int lane = tid & 63;
    const int lrow = lane >> 3;
    const int lcol = lane & 7;
    const int wm = (wave >> 1) * 64;
    const int wn = (wave & 1) * 64;
    const int fr = lane & 15;
    const int fg = lane >> 4;

    for (int k0 = 0; k0 < K; k0 += 64) {
#pragma unroll
        for (int r = 0; r < 4; ++r) {
            int row = r * 32 + wave * 8 + lrow;
            async16(A + (size_t)(m0 + row) * lda + k0 + lcol * 8, ldsA + r * 2048 + wave * 512);
            async16(Bt + (size_t)(n0 + row) * ldb + k0 + lcol * 8, ldsB + r * 2048 + wave * 512);
        }
        __syncthreads();
#pragma unroll
        for (int ks = 0; ks < 2; ++ks) {
            bf16x8 af[4], bfr[4];
#pragma unroll
            for (int mf = 0; mf < 4; ++mf)
                af[mf] = *reinterpret_cast<const bf16x8*>(ldsA + (wm + mf * 16 + fr) * 64 + ks * 32 + fg * 8);
#pragma unroll
            for (int nf = 0; nf < 4; ++nf)
                bfr[nf] = *reinterpret_cast<const bf16x8*>(ldsB + (wn + nf * 16 + fr) * 64 + ks * 32 + fg * 8);
#pragma unroll
            for (int mf = 0; mf < 4; ++mf)
#pragma unroll
                for (int nf = 0; nf < 4; ++nf)
                    acc[mf][nf] = __builtin_amdgcn_mfma_f32_16x16x32_bf16(af[mf], bfr[nf], acc[mf][nf], 0, 0, 0);
        }
        __syncthreads();
    }
}

// ---------------- K1 (fused): blocks 0-63: Mt8 = perm-fp8(64*Wk Wq^T);
//                  blocks 64+: x -> bf16 + perm-fp8, c[row] = scale*x.u ----
__global__ __launch_bounds__(256) void k_cvtx_mm(const float* __restrict__ x,
                                                 const float* __restrict__ u,
                                                 const unsigned short* __restrict__ wkb,
                                                 const unsigned short* __restrict__ wqb,
                                                 unsigned short* __restrict__ xb,
                                                 unsigned char* __restrict__ xb8,
                                                 float* __restrict__ c,
                                                 unsigned char* __restrict__ Mt8) {
    __shared__ unsigned short ldsA[8192];
    __shared__ unsigned short ldsB[8192];
    const int bid = blockIdx.x;
    if (bid < 64) {
        int m0 = (bid & 7) * 128, n0 = (bid >> 3) * 128;
        f32x4 acc[4][4] = {};
        gemm_bt_tile128(wkb, wqb, DIM, m0, n0, DIM, DIM, ldsA, ldsB, acc);
        const int lane = threadIdx.x & 63, wave = threadIdx.x >> 6;
        const int wm = (wave >> 1) * 64, wn = (wave & 1) * 64;
        const int fr = lane & 15, fg = lane >> 4;
#pragma unroll
        for (int nf = 0; nf < 4; ++nf) {
            int n = n0 + wn + nf * 16 + fr;
            int pn = perm128(n);
#pragma unroll
            for (int mf = 0; mf < 4; ++mf) {
                int r0 = m0 + wm + mf * 16 + fg * 4;
                int pk01 = __builtin_amdgcn_cvt_pk_fp8_f32(acc[mf][nf][0] * 64.f, acc[mf][nf][1] * 64.f, 0, false);
                int pk23 = __builtin_amdgcn_cvt_pk_fp8_f32(acc[mf][nf][2] * 64.f, acc[mf][nf][3] * 64.f, 0, false);
                Mt8[(size_t)(r0 + 0) * DIM + pn] = (unsigned char)(pk01 & 0xff);
                Mt8[(size_t)(r0 + 1) * DIM + pn] = (unsigned char)((pk01 >> 8) & 0xff);
                Mt8[(size_t)(r0 + 2) * DIM + pn] = (unsigned char)(pk23 & 0xff);
                Mt8[(size_t)(r0 + 3) * DIM + pn] = (unsigned char)((pk23 >> 8) & 0xff);
            }
        }
    } else {
        float* red = (float*)ldsA;
        const int row = bid - 64, tid = threadIdx.x;
        size_t i = (size_t)row * DIM + tid * 4;
        float4 v = *reinterpret_cast<const float4*>(x + i);
        ushort4 o;
        o.x = f2bf(v.x); o.y = f2bf(v.y); o.z = f2bf(v.z); o.w = f2bf(v.w);
        *reinterpret_cast<ushort4*>(xb + i) = o;
        int pk = __builtin_amdgcn_cvt_pk_fp8_f32(v.x, v.y, 0, false);
        pk = __builtin_amdgcn_cvt_pk_fp8_f32(v.z, v.w, pk, true);
        int pp = perm128(tid * 4);   // 4 elems stay in one dword chunk
        *reinterpret_cast<unsigned int*>(xb8 + (size_t)row * DIM + pp) = (unsigned int)pk;
        float4 uv = *reinterpret_cast<const float4*>(u + tid * 4);
        float s = v.x * uv.x + v.y * uv.y + v.z * uv.z + v.w * uv.w;
#pragma unroll
        for (int off = 32; off; off >>= 1) s += __shfl_xor(s, off);
        if ((tid & 63) == 0) red[tid >> 6] = s;
        __syncthreads();
        if (tid == 0) c[row] = 0.03125f * (red[0] + red[1] + red[2] + red[3]);
    }
}

// ---------------------------------------------------------------------------
// 256x256 fp8 GEMM core. K = 1024, BK = 128 fp8 (permuted rows). Fragment
// reads = forced ds_read_b128 at col h*64+fg*16 (bf16-core bank pattern,
// measured conflict-free). 8 K-tiles, 4 iters, 1 barrier/phase, vmcnt(4).
// ---------------------------------------------------------------------------

#define STAGE8(gbase, ld, dstoff)                                         \
    do {                                                                  \
        async16b((gbase), ldsw + (dstoff));                               \
        async16b((gbase) + 8 * (size_t)(ld), ldsw + (dstoff) + 1024);     \
    } while (0)
#define STAGE8_A(buf, half, kt) STAGE8(gA + (size_t)((half) * 128) * lda + (kt) * 128, lda, (buf) * 32768 + (half) * 16384)
#define STAGE8_B(buf, half, kt) STAGE8(gB + (size_t)((half) * 128) * ldb + (kt) * 128, ldb, 65536 + (buf) * 32768 + (half) * 16384)

#define FRAG8(base_b, row, colb) \
    ds_read128(lds, (base_b) + (row) * 128 + ((colb) ^ (((row) & 7) << 4)))

#define READ8_A(dbuf, mh)                                                     \
    _Pragma("unroll") for (int m2 = 0; m2 < 4; ++m2) {                        \
        int arow = ((mh) * 4 + m2) * 16 + fr;                                 \
        _Pragma("unroll") for (int h = 0; h < 2; ++h)                         \
            afc[(mh) * 4 + m2][h] =                                           \
                FRAG8((dbuf) * 32768 + wr * 16384, arow, h * 64 + fg * 16);   \
    }
#define READ8_B(dbuf, nh)                                                     \
    _Pragma("unroll") for (int n2 = 0; n2 < 2; ++n2) {                        \
        int brow = (wc & 1) * 64 + ((nh) * 2 + n2) * 16 + fr;                 \
        _Pragma("unroll") for (int h = 0; h < 2; ++h)                         \
            bfc[nh][n2][h] =                                                  \
                FRAG8(65536 + (dbuf) * 32768 + (wc >> 1) * 16384, brow,       \
                      h * 64 + fg * 16);                                      \
    }

#define VM4 asm volatile("s_waitcnt vmcnt(4)" ::: "memory")

#define PHASE8(mh, nh, STG, VM, PF)                                           \
    do {                                                                      \
        STG;                                                                  \
        VM;                                                                   \
        asm volatile("s_barrier" ::: "memory");                               \
        asm volatile("s_waitcnt lgkmcnt(0)" ::: "memory");                    \
        __builtin_amdgcn_sched_barrier(0);                                    \
        PF;                                                                   \
        __builtin_amdgcn_sched_barrier(0);                                    \
        __builtin_amdgcn_s_setprio(1);                                        \
        _Pragma("unroll") for (int m2 = 0; m2 < 4; ++m2)                      \
        _Pragma("unroll") for (int n2 = 0; n2 < 2; ++n2) {                    \
            f32x4& a = acc[(mh) * 4 + m2][(nh) * 2 + n2];                     \
            a = mfma8(afc[(mh) * 4 + m2][0][0], bfc[nh][n2][0][0], a);        \
            a = mfma8(afc[(mh) * 4 + m2][0][1], bfc[nh][n2][0][1], a);        \
            a = mfma8(afc[(mh) * 4 + m2][1][0], bfc[nh][n2][1][0], a);        \
            a = mfma8(afc[(mh) * 4 + m2][1][1], bfc[nh][n2][1][1], a);        \
        }                                                                     \
        __builtin_amdgcn_s_setprio(0);                                        \
    } while (0)

__device__ __forceinline__ void gemm256_fp8(const unsigned char* __restrict__ A,
                                            const unsigned char* __restrict__ Bt,
                                            int lda, int ldb, int m0, int n0,
                                            unsigned char* lds, f32x4 (&acc)[8][4]) {
    constexpr int NKT = 1024 / 128;  // 8 K-tiles
    constexpr int NIT = NKT / 2;     // 4 iterations
    const int tid = threadIdx.x;
    const int w = tid >> 6, lane = tid & 63;
    const int wr = w >> 2, wc = w & 3;
    const int fr = lane & 15, fg = lane >> 4;
    const int r8 = lane >> 3, slot = (lane & 7) ^ r8;

    const unsigned char* gA = A + (size_t)(m0 + w * 16 + r8) * lda + slot * 16;
    const unsigned char* gB = Bt + (size_t)(n0 + w * 16 + r8) * ldb + slot * 16;
    unsigned char* ldsw = lds + w * 2048;

    i64x2 afc[8][2];
    i64x2 bfc[2][2][2];

    STAGE8_A(0, 0, 0); STAGE8_A(0, 1, 0); STAGE8_B(0, 0, 0); STAGE8_B(0, 1, 0);
    STAGE8_A(1, 0, 1); STAGE8_A(1, 1, 1);
    VM4;
    asm volatile("s_barrier" ::: "memory");
    READ8_A(0, 0); READ8_B(0, 0);

    for (int it = 0; it < NIT; ++it) {
        const int t1 = 2 * it + 1;
        const int ka = (2 * it + 2) & (NKT - 1);
        const int kb = (2 * it + 3) & (NKT - 1);
        PHASE8(0, 0, STAGE8_B(1, 0, t1), , READ8_A(0, 1));
        PHASE8(1, 0, STAGE8_B(1, 1, t1), , READ8_B(0, 1));
        PHASE8(0, 1, STAGE8_A(0, 0, ka), , );
        PHASE8(1, 1, STAGE8_A(0, 1, ka), VM4, READ8_A(1, 0); READ8_B(1, 0));
        PHASE8(0, 0, STAGE8_B(0, 0, ka), , READ8_A(1, 1));
        PHASE8(1, 0, STAGE8_B(0, 1, ka), , READ8_B(1, 1));
        PHASE8(0, 1, STAGE8_A(1, 0, kb), , );
        PHASE8(1, 1, STAGE8_A(1, 1, kb), VM4, READ8_A(0, 0); READ8_B(0, 0));
    }
    asm volatile("s_waitcnt vmcnt(0) lgkmcnt(0)" ::: "memory");
}

// ---------------- K2: y8 = permuted fp8(8*y)  (A=xb8, Bt=Mt8) ----------------
__global__ __launch_bounds__(512, 1) void k_proj_y(const unsigned char* __restrict__ xb8,
                                                   const unsigned char* __restrict__ Mt8,
                                                   unsigned char* __restrict__ y8) {
    __shared__ unsigned char lds[131072];   // 128 KiB
    const int f = blockIdx.x;
    const int m_hi = f & 7, j = f >> 3;
    const int n_t = j & 3, m_lo = j >> 2;
    const int m0 = (m_hi * 8 + m_lo) * 256, n0 = n_t * 256;

    f32x4 acc[8][4] = {};
    gemm256_fp8(xb8, Mt8, DIM, DIM, m0, n0, lds, acc);

    const int tid = threadIdx.x, w = tid >> 6, lane = tid & 63;
    const int wr = w >> 2, wc = w & 3, fr = lane & 15, fg = lane >> 4;
#pragma unroll
    for (int nf = 0; nf < 4; ++nf) {
        int n = n0 + wc * 64 + nf * 16 + fr;
        int pn = perm128(n);
#pragma unroll
        for (int mf = 0; mf < 8; ++mf) {
            int r0 = m0 + wr * 128 + mf * 16 + fg * 4;
            int pk01 = __builtin_amdgcn_cvt_pk_fp8_f32(acc[mf][nf][0] * 0.125f, acc[mf][nf][1] * 0.125f, 0, false);
            int pk23 = __builtin_amdgcn_cvt_pk_fp8_f32(acc[mf][nf][2] * 0.125f, acc[mf][nf][3] * 0.125f, 0, false);
            y8[(size_t)(r0 + 0) * DIM + pn] = (unsigned char)(pk01 & 0xff);
            y8[(size_t)(r0 + 1) * DIM + pn] = (unsigned char)((pk01 >> 8) & 0xff);
            y8[(size_t)(r0 + 2) * DIM + pn] = (unsigned char)(pk23 & 0xff);
            y8[(size_t)(r0 + 3) * DIM + pn] = (unsigned char)((pk23 >> 8) & 0xff);
        }
    }
}

// ---------------- K3: PT[t][s] = fp8(exp(acc*scl/8 + c[t])), ell[s] = rowsum ----------------
__global__ __launch_bounds__(512, 1) void k_scores(const unsigned char* __restrict__ y8,
                                                   const unsigned char* __restrict__ xb8,
                                                   const float* __restrict__ c,
                                                   unsigned char* __restrict__ PT,
                                                   float* __restrict__ ell) {
    __shared__ unsigned char lds[131072];
    const int f = blockIdx.x;
    const int b = f & 7, j = f >> 3;
    const int mt = j & 7, nt = j >> 3;
    const unsigned char* q = y8 + (size_t)b * SEQ * DIM;
    const unsigned char* k = xb8 + (size_t)b * SEQ * DIM;
    const int m0 = mt * 256, n0 = nt * 256;

    f32x4 acc[8][4] = {};
    gemm256_fp8(q, k, DIM, DIM, m0, n0, lds, acc);

    const float scl8 = 0.00390625f;  // (1/32)/8 : y8 carries 8x
    const int tid = threadIdx.x, w = tid >> 6, lane = tid & 63;
    const int wr = w >> 2, wc = w & 3, fr = lane & 15, fg = lane >> 4;
    unsigned char* Pb = PT + (size_t)b * SEQ * SEQ;
    float cv[4];
#pragma unroll
    for (int nf = 0; nf < 4; ++nf)
        cv[nf] = c[(size_t)b * SEQ + n0 + wc * 64 + nf * 16 + fr];
#pragma unroll
    for (int mf = 0; mf < 8; ++mf) {
        const int sbase = m0 + wr * 128 + mf * 16 + fg * 4;
        float rs[4] = {0.f, 0.f, 0.f, 0.f};
#pragma unroll
        for (int nf = 0; nf < 4; ++nf) {
            int t = n0 + wc * 64 + nf * 16 + fr;
            float p0 = __expf(fmaf(acc[mf][nf][0], scl8, cv[nf]));
            float p1 = __expf(fmaf(acc[mf][nf][1], scl8, cv[nf]));
            float p2 = __expf(fmaf(acc[mf][nf][2], scl8, cv[nf]));
            float p3 = __expf(fmaf(acc[mf][nf][3], scl8, cv[nf]));
            int pk = __builtin_amdgcn_cvt_pk_fp8_f32(p0, p1, 0, false);
            pk = __builtin_amdgcn_cvt_pk_fp8_f32(p2, p3, pk, true);
            *reinterpret_cast<unsigned int*>(Pb + (size_t)t * SEQ + sbase) = (unsigned int)pk;
            f32x2 d01 = __builtin_amdgcn_cvt_pk_f32_fp8(pk, false);
            f32x2 d23 = __builtin_amdgcn_cvt_pk_f32_fp8(pk, true);
            rs[0] += d01[0]; rs[1] += d01[1]; rs[2] += d23[0]; rs[3] += d23[1];
        }
#pragma unroll
        for (int j2 = 0; j2 < 4; ++j2) {
            float r = rs[j2];
            r += __shfl_xor(r, 1);
            r += __shfl_xor(r, 2);
            r += __shfl_xor(r, 4);
            r += __shfl_xor(r, 8);
            if (fr == 0) atomicAdd(&ell[b * SEQ + sbase + j2], r);
        }
    }
}

// ---------------- K4: w[t] = sum_s PT[t][s] / ell[s] ----------------
__global__ __launch_bounds__(256) void k_colsum(const unsigned char* __restrict__ PT,
                                                const float* __restrict__ ell,
                                                float* __restrict__ w) {
    __shared__ float rel[512];
    const int b = blockIdx.z;
    const int s0 = blockIdx.x * 512;
    const int t = blockIdx.y * 256 + threadIdx.x;
    {
        int i = threadIdx.x;
        rel[i]       = 1.0f / ell[b * SEQ + s0 + i];
        rel[i + 256] = 1.0f / ell[b * SEQ + s0 + 256 + i];
    }
    __syncthreads();
    const unsigned char* Pt = PT + (size_t)b * SEQ * SEQ + (size_t)t * SEQ + s0;
    float a = 0.f;
    for (int i = 0; i < 512; i += 8) {
        uint2 pv = *reinterpret_cast<const uint2*>(Pt + i);
        f32x2 d0 = __builtin_amdgcn_cvt_pk_f32_fp8((int)pv.x, false);
        f32x2 d1 = __builtin_amdgcn_cvt_pk_f32_fp8((int)pv.x, true);
        f32x2 d2 = __builtin_amdgcn_cvt_pk_f32_fp8((int)pv.y, false);
        f32x2 d3 = __builtin_amdgcn_cvt_pk_f32_fp8((int)pv.y, true);
        a += d0[0] * rel[i]     + d0[1] * rel[i + 1] + d1[0] * rel[i + 2] + d1[1] * rel[i + 3];
        a += d2[0] * rel[i + 4] + d2[1] * rel[i + 5] + d3[0] * rel[i + 6] + d3[1] * rel[i + 7];
    }
    atomicAdd(&w[b * SEQ + t], a);
}

// ---------------- K5: g[b,d] = (1/S) sum_t w[b,t] * xb[b,t,d]  (bf16 x) ----------------
__global__ __launch_bounds__(256) void k_accx(const float* __restrict__ w,
                                              const unsigned short* __restrict__ xb,
                                              float* __restrict__ g) {
    const int b = blockIdx.y;
    const int t0 = blockIdx.x * 64 + (threadIdx.x >> 7) * 32;
    const int d8 = (threadIdx.x & 127) * 8;
    const unsigned short* xbb = xb + (size_t)b * SEQ * DIM;
    const float* wb = w + b * SEQ;
    float a[8] = {};
    for (int i = 0; i < 32; ++i) {
        int t = t0 + i;
        float wt = wb[t];
        u16x8 v = *reinterpret_cast<const u16x8*>(xbb + (size_t)t * DIM + d8);
#pragma unroll
        for (int j = 0; j < 8; ++j) a[j] += wt * bf2f(v[j]);
    }
#pragma unroll
    for (int j = 0; j < 8; ++j)
        atomicAdd(&g[b * DIM + d8 + j], a[j] * (1.0f / (float)SEQ));
}

// ---------------- K6: out[b,n] += sum_{d in chunk} g[b,d] * Wv[d,n] ----------------
__global__ __launch_bounds__(256) void k_out2(const float* __restrict__ g,
                                              const float* __restrict__ Wv,
                                              float* __restrict__ out) {
    int b = blockIdx.y;
    int n = blockIdx.x * 256 + threadIdx.x;
    int d0 = blockIdx.z * 64;
    const float* gb = g + b * DIM;
    float acc = 0.f;
#pragma unroll
    for (int d = 0; d < 64; ++d)
        acc += gb[d0 + d] * Wv[(size_t)(d0 + d) * DIM + n];
    atomicAdd(&out[b * DIM + n], acc);
}

extern "C" void kernel_launch(void* const* d_in, const int* in_sizes, int n_in,
                              void* d_out, int out_size, void* d_ws, size_t ws_size,
                              hipStream_t stream) {
    const float* x  = (const float*)d_in[0];
    const float* Wq = (const float*)d_in[1];
    const float* bq = (const float*)d_in[2];
    const float* Wk = (const float*)d_in[3];
    const float* bk = (const float*)d_in[4];   // unused (softmax-invariant)
    const float* Wv = (const float*)d_in[5];
    const float* bv = (const float*)d_in[6];
    float* out = (float*)d_out;
    (void)bk;

    char* ws = (char*)d_ws;
    unsigned short* xb  = (unsigned short*)(ws);                    //  33,554,432
    unsigned short* wkb = (unsigned short*)(ws + 33554432ull);      //   2,097,152
    unsigned short* wqb = (unsigned short*)(ws + 35651584ull);      //   2,097,152
    unsigned char*  Mt8 = (unsigned char*)(ws + 37748736ull);       //   1,048,576
    unsigned char*  xb8 = (unsigned char*)(ws + 38797312ull);       //  16,777,216
    unsigned char*  y8  = (unsigned char*)(ws + 55574528ull);       //  16,777,216
    unsigned char*  PT  = (unsigned char*)(ws + 72351744ull);       //  33,554,432
    float*          ell = (float*)(ws + 105906176ull);              //      65,536
    float*          w   = (float*)(ws + 105971712ull);              //      65,536
    float*          g   = (float*)(ws + 106037248ull);              //      32,768
    float*          c   = (float*)(ws + 106070016ull);              //      65,536
    float*          u   = (float*)(ws + 106135552ull);              //       4,096

    // ell+w+g zeroed by k_prep blocks 2336..2495 (40960 floats, contiguous)
    k_prep<<<dim3(2496), 256, 0, stream>>>(Wk, Wq, bq, bv, wkb, wqb, u, out, ell);
    k_cvtx_mm<<<dim3(64 + MTOT), 256, 0, stream>>>(x, u, wkb, wqb, xb, xb8, c, Mt8);
    k_proj_y<<<dim3(256), 512, 0, stream>>>(xb8, Mt8, y8);
    k_scores<<<dim3(512), 512, 0, stream>>>(y8, xb8, c, PT, ell);
    k_colsum<<<dim3(SEQ / 512, SEQ / 256, NB), 256, 0, stream>>>(PT, ell, w);
    k_accx<<<dim3(SEQ / 64, NB), 256, 0, stream>>>(w, xb, g);
    k_out2<<<dim3(DIM / 256, NB, 16), 256, 0, stream>>>(g, Wv, out);
}